// Round 4
// baseline (877.801 us; speedup 1.0000x reference)
//
#include <hip/hip_runtime.h>

#define T_DIM 2048
#define B_DIM 16
#define E_DIM 1024
#define CD    1024
#define NH    16
#define KSZ   31
#define M_DIM 32768
#define SLICE 131072            // 2048*64 elements per (b,h) slice
#define BSTRIDE 2097152         // 2048*1024 = 16*SLICE

typedef unsigned int u32;
typedef unsigned short u16;
typedef __attribute__((ext_vector_type(8))) __bf16 bf16x8;
typedef __attribute__((ext_vector_type(4))) float f32x4;
typedef __attribute__((ext_vector_type(4))) float fvec4;
typedef __attribute__((ext_vector_type(8))) unsigned short us8;
typedef __attribute__((ext_vector_type(4))) unsigned short us4;
typedef __attribute__((ext_vector_type(4))) unsigned int ui4;

__device__ __forceinline__ float bf2f(u16 u) {
  union { float f; u32 i; } c; c.i = ((u32)u) << 16; return c.f;
}
__device__ __forceinline__ u16 f2bf(float f) {
  union { float f; u32 i; } c; c.f = f;
  u32 u = c.i;
  u += 0x7fffu + ((u >> 16) & 1u);   // RNE
  return (u16)(u >> 16);
}

#define GLDS(gp, lp)                                                        \
  __builtin_amdgcn_global_load_lds(                                         \
      (__attribute__((address_space(1))) void*)(gp),                        \
      (__attribute__((address_space(3))) void*)(lp), 16, 0, 0)

// ---------------------------------------------------------------- zero scratch (4 KB)
__global__ __launch_bounds__(256) void zfill(u16* __restrict__ z) {
  ((ui4*)z)[threadIdx.x] = (ui4)(0u);
}

// ---------------------------------------------------------------- cvt f32->bf16 (weights)
__global__ __launch_bounds__(256) void cvt_f32_bf16(const float* __restrict__ src,
                                                    u16* __restrict__ dst, int n4) {
  int i = blockIdx.x * 256 + threadIdx.x;
  int stride = gridDim.x * 256;
  const fvec4* s4 = (const fvec4*)src;
  us4* d4 = (us4*)dst;
  for (; i < n4; i += stride) {
    fvec4 v = s4[i];
    us4 o;
    o[0] = f2bf(v[0]); o[1] = f2bf(v[1]); o[2] = f2bf(v[2]); o[3] = f2bf(v[3]);
    d4[i] = o;
  }
}

// ---------------------------------------------------------------- cvt + row-permute x: [t][b][e] f32 -> [b][t][e] bf16
__global__ __launch_bounds__(256) void cvt_x_tr(const float* __restrict__ x,
                                                u16* __restrict__ xbt) {
  int rr = blockIdx.x;           // t*16+b
  int t = rr >> 4, b = rr & 15;
  const fvec4* src = (const fvec4*)(x + (size_t)rr * E_DIM);
  us4* dst = (us4*)(xbt + ((size_t)b * T_DIM + t) * E_DIM);
  fvec4 v = src[threadIdx.x];
  us4 o;
  o[0] = f2bf(v[0]); o[1] = f2bf(v[1]); o[2] = f2bf(v[2]); o[3] = f2bf(v[3]);
  dst[threadIdx.x] = o;
}

// ---------------------------------------------------------------- bf16 MFMA GEMM (B^T layout), rows indexed m' = b*2048+t
// C[M,N] = A[M,K] * B[N,K]^T + bias.  128x128 tile, BK=32, 4 waves (2x2 of 64x64).
// A_CONV: 0 = row-major stride K; 1 = conv layout A[(b*16 + k/64)*SLICE + t*64 + k%64].
// OUT_MODE: 1 = bf16 row-major (ldc); 2 = wt[b][h][t][32] f32; 3 = conv-layout bf16.
template<int OUT_MODE, int GUARD_N, int A_CONV>
__global__ __launch_bounds__(256) void gemm_bt(
    const u16* __restrict__ A, const u16* __restrict__ B,
    const float* __restrict__ bias, void* __restrict__ Cout,
    int N, int K, int ldc, int ntn)
{
  constexpr int BK = 32;
  __shared__ u16 sA[128 * BK];
  __shared__ u16 sB[128 * BK];
  const int tid = threadIdx.x;
  const int lane = tid & 63;
  const int wid = tid >> 6;
  const int bm = (blockIdx.x / ntn) * 128;
  const int bn = (blockIdx.x % ntn) * 128;
  const int wr = (wid >> 1) * 64;
  const int wc = (wid & 1) * 64;

  const int srow = tid >> 2;            // 0..63
  const int skoff = (tid & 3) * 8;      // k element offset (0..24)
  const int rr0 = bm + srow, rr1 = bm + srow + 64;
  const u16 *pA0, *pA1;
  if (A_CONV) {
    pA0 = A + (size_t)(rr0 >> 11) * BSTRIDE + (size_t)(rr0 & 2047) * 64 + skoff;
    pA1 = A + (size_t)(rr1 >> 11) * BSTRIDE + (size_t)(rr1 & 2047) * 64 + skoff;
  } else {
    pA0 = A + (size_t)rr0 * K + skoff;
    pA1 = A + (size_t)rr1 * K + skoff;
  }
  int brow0 = bn + srow, brow1 = bn + srow + 64;
  if (GUARD_N) { brow0 = min(brow0, N - 1); brow1 = min(brow1, N - 1); }
  const u16* pB0 = B + (size_t)brow0 * K + skoff;
  const u16* pB1 = B + (size_t)brow1 * K + skoff;

  u16* lA0 = sA + wid * 512;            // wave-uniform LDS bases
  u16* lA1 = sA + 2048 + wid * 512;
  u16* lB0 = sB + wid * 512;
  u16* lB1 = sB + 2048 + wid * 512;

  f32x4 acc[4][4];
  #pragma unroll
  for (int i = 0; i < 4; i++)
    #pragma unroll
    for (int j = 0; j < 4; j++) acc[i][j] = (f32x4)(0.0f);

  const int fr = lane & 15;
  const int fk = (lane >> 4) * 8;

  for (int k0 = 0; k0 < K; k0 += BK) {
    const u16 *ga0, *ga1;
    if (A_CONV) {
      int ko = (k0 >> 6) * SLICE + (k0 & 32);
      ga0 = pA0 + ko; ga1 = pA1 + ko;
    } else {
      ga0 = pA0 + k0; ga1 = pA1 + k0;
    }
    __syncthreads();
    GLDS(ga0, lA0);
    GLDS(ga1, lA1);
    GLDS(pB0 + k0, lB0);
    GLDS(pB1 + k0, lB1);
    __syncthreads();
    bf16x8 aF[4], bF[4];
    #pragma unroll
    for (int m = 0; m < 4; m++)
      aF[m] = *(const bf16x8*)(sA + (wr + m * 16 + fr) * BK + fk);
    #pragma unroll
    for (int n = 0; n < 4; n++)
      bF[n] = *(const bf16x8*)(sB + (wc + n * 16 + fr) * BK + fk);
    #pragma unroll
    for (int m = 0; m < 4; m++)
      #pragma unroll
      for (int n = 0; n < 4; n++)
        acc[m][n] = __builtin_amdgcn_mfma_f32_16x16x32_bf16(aF[m], bF[n], acc[m][n], 0, 0, 0);
  }

  const int orow = bm + wr + (lane >> 4) * 4;   // C/D: col=lane&15, row=(lane>>4)*4+q
  const int ocol = bn + wc + fr;
  #pragma unroll
  for (int m = 0; m < 4; m++) {
    #pragma unroll
    for (int n = 0; n < 4; n++) {
      #pragma unroll
      for (int q = 0; q < 4; q++) {
        int row = orow + m * 16 + q;
        int col = ocol + n * 16;
        if (!GUARD_N || col < N) {
          float v = acc[m][n][q] + bias[col];
          if (OUT_MODE == 1) {
            ((u16*)Cout)[(size_t)row * ldc + col] = f2bf(v);
          } else if (OUT_MODE == 2) {
            int bb = row >> 11, t = row & 2047;
            int hh = col / 31, kk = col - hh * 31;      // compile-time magic div
            ((float*)Cout)[((size_t)((bb * NH + hh) * T_DIM + t)) * 32 + kk] = v;
          } else {                                       // 3: conv layout bf16
            int bb = row >> 11, t = row & 2047;
            ((u16*)Cout)[(size_t)((bb << 4) + (col >> 6)) * SLICE + (size_t)t * 64 + (col & 63)] = f2bf(v);
          }
        }
      }
    }
  }
}

// ---------------------------------------------------------------- softmax over K=31, in place on wt rows
__global__ __launch_bounds__(256) void softmax31(float* __restrict__ wt) {
  int idx = blockIdx.x * 256 + threadIdx.x;   // one row (b,h,t) per thread
  float* p = wt + (size_t)idx * 32;
  float v[KSZ];
  float mx = -1e30f;
  #pragma unroll
  for (int k = 0; k < KSZ; k++) { v[k] = p[k]; mx = fmaxf(mx, v[k]); }
  float s = 0.f;
  #pragma unroll
  for (int k = 0; k < KSZ; k++) { v[k] = __expf(v[k] - mx); s += v[k]; }
  float inv = 1.0f / s;
  #pragma unroll
  for (int k = 0; k < KSZ; k++) p[k] = v[k] * inv;
}

// ---------------------------------------------------------------- dynamic conv (conv-layout, streaming)
// h1'[s][t][64] with s=b*16+h. Block: 64 t for one slice s. Thread: 8 ch x 2 t.
// h-tile: one contiguous 12 KB global_load_lds region; w: broadcast f32x4 from wt;
// out: contiguous 8 KB per block.
__global__ __launch_bounds__(256, 4) void dconv(const u16* __restrict__ h1,
                                                const float* __restrict__ wt,
                                                const u16* __restrict__ zreg,
                                                u16* __restrict__ outc)
{
  constexpr int TT = 64, HALO = 30;
  int bid = blockIdx.x;
  int tt = bid & 31;            // T/64 = 32
  int s  = bid >> 5;            // b*16+h, 0..255
  int t0 = tt * TT;
  __shared__ u16 hl[96 * 64];   // rows t0-30 .. t0+65 (rows 94,95 staged-but-unused), 12 KB
  int tid = threadIdx.x;

  const u16* slice = h1 + (size_t)s * SLICE;
  #pragma unroll
  for (int it = 0; it < 3; it++) {
    int c = it * 256 + tid;
    int row = t0 - HALO + (c >> 3);
    const u16* src = slice + (size_t)row * 64 + (c & 7) * 8;
    if (row < 0) src = zreg + (c & 7) * 8;      // zeroed scratch
    GLDS(src, hl + c * 8);
  }
  __syncthreads();

  int rb = (tid & 7) * 8;           // channel sub-block
  int tl = (tid >> 3) * 2;          // 2 consecutive local t per thread
  const float* wp = wt + ((size_t)s * T_DIM + t0 + tl) * 32;
  const u16* hbase = hl + tl * 64 + rb;

  float acca[8], accb[8];
  #pragma unroll
  for (int e = 0; e < 8; e++) { acca[e] = 0.f; accb[e] = 0.f; }
  float wbprev = 0.f;

  #pragma unroll
  for (int rr4 = 0; rr4 < 8; rr4++) {
    f32x4 wa = *(const f32x4*)(wp + rr4 * 4);          // taps for out t=tl
    f32x4 wb = *(const f32x4*)(wp + 32 + rr4 * 4);     // taps for out t=tl+1
    #pragma unroll
    for (int j = 0; j < 4; j++) {
      const int rr = rr4 * 4 + j;                      // input row tl+rr
      us8 hv = *(const us8*)(hbase + rr * 64);
      float hf[8];
      #pragma unroll
      for (int e = 0; e < 8; e++) hf[e] = bf2f(hv[e]);
      if (rr < 31) {
        float w = wa[j];
        #pragma unroll
        for (int e = 0; e < 8; e++) acca[e] += w * hf[e];
      }
      if (rr >= 1) {
        float w = (j == 0) ? wbprev : wb[j - 1];
        #pragma unroll
        for (int e = 0; e < 8; e++) accb[e] += w * hf[e];
      }
    }
    wbprev = wb[3];
  }

  us8 oa, ob;
  #pragma unroll
  for (int e = 0; e < 8; e++) { oa[e] = f2bf(acca[e]); ob[e] = f2bf(accb[e]); }
  u16* obase = outc + (size_t)s * SLICE + (size_t)(t0 + tl) * 64 + rb;
  *(us8*)obase = oa;
  *(us8*)(obase + 64) = ob;
}

// ---------------------------------------------------------------- residual + LayerNorm
// h2'[m'][e] (m' = b*2048+t, bf16) + x[t*16+b][e] (f32) -> out[t*16+b][e] (f32)
__global__ __launch_bounds__(256) void ln_res(const float* __restrict__ x,
                                              const u16* __restrict__ hb,
                                              float* __restrict__ out,
                                              const float* __restrict__ gamma,
                                              const float* __restrict__ beta)
{
  int mp = blockIdx.x;                 // b*2048 + t
  int b = mp >> 11, t = mp & 2047;
  int xrow = t * 16 + b;
  const fvec4* xr = (const fvec4*)(x + (size_t)xrow * E_DIM);
  const us4* hr = (const us4*)(hb + (size_t)mp * E_DIM);
  fvec4* yr = (fvec4*)(out + (size_t)xrow * E_DIM);
  int tid = threadIdx.x;
  us4 hv = hr[tid];
  fvec4 xv = xr[tid];
  fvec4 s;
  #pragma unroll
  for (int e = 0; e < 4; e++) s[e] = xv[e] + bf2f(hv[e]);
  float sum = s[0] + s[1] + s[2] + s[3];
  float sq  = s[0]*s[0] + s[1]*s[1] + s[2]*s[2] + s[3]*s[3];
  #pragma unroll
  for (int off = 32; off >= 1; off >>= 1) {
    sum += __shfl_xor(sum, off, 64);
    sq  += __shfl_xor(sq, off, 64);
  }
  __shared__ float red[8];
  int lane = tid & 63, wid = tid >> 6;
  if (lane == 0) { red[wid] = sum; red[4 + wid] = sq; }
  __syncthreads();
  sum = red[0] + red[1] + red[2] + red[3];
  sq  = red[4] + red[5] + red[6] + red[7];
  float mean = sum * (1.0f / E_DIM);
  float var  = sq * (1.0f / E_DIM) - mean * mean;
  float rstd = rsqrtf(var + 1e-5f);
  fvec4 g = ((const fvec4*)gamma)[tid];
  fvec4 be = ((const fvec4*)beta)[tid];
  fvec4 o;
  #pragma unroll
  for (int e = 0; e < 4; e++) o[e] = (s[e] - mean) * rstd * g[e] + be[e];
  yr[tid] = o;
}

// ---------------------------------------------------------------- launcher
extern "C" void kernel_launch(void* const* d_in, const int* in_sizes, int n_in,
                              void* d_out, int out_size, void* d_ws, size_t ws_size,
                              hipStream_t stream)
{
  const float* x     = (const float*)d_in[0];
  const float* w1    = (const float*)d_in[1];
  const float* b1    = (const float*)d_in[2];
  const float* ww    = (const float*)d_in[3];
  const float* bw    = (const float*)d_in[4];
  const float* w2    = (const float*)d_in[5];
  const float* b2    = (const float*)d_in[6];
  const float* gamma = (const float*)d_in[7];
  const float* beta  = (const float*)d_in[8];
  float* out = (float*)d_out;

  char* ws = (char*)d_ws;
  u16*   xbt  = (u16*)(ws);                          // 64 MB  xb'[b][t][e]; reused as conv'
  u16*   h1p  = (u16*)(ws + ((size_t)64 << 20));     // 64 MB  h1'[s][t][64]; reused as h2'
  float* wt   = (float*)(ws + ((size_t)128 << 20));  // 64 MB  wt[b][h][t][32] f32
  u16*   w1b  = (u16*)(ws + ((size_t)192 << 20));    // 2 MB
  u16*   w2b  = (u16*)(ws + ((size_t)194 << 20));    // 2 MB
  u16*   wwb  = (u16*)(ws + ((size_t)196 << 20));    // ~1 MB
  u16*   zreg = (u16*)(ws + ((size_t)198 << 20));    // 4 KB zeroed
  u16*   convp = xbt;
  u16*   h2p  = h1p;

  zfill<<<1, 256, 0, stream>>>(zreg);
  cvt_x_tr<<<32768, 256, 0, stream>>>(x, xbt);
  cvt_f32_bf16<<<1024, 256, 0, stream>>>(w1, w1b, (CD * E_DIM) / 4);
  cvt_f32_bf16<<<1024, 256, 0, stream>>>(w2, w2b, (E_DIM * CD) / 4);
  cvt_f32_bf16<<<512,  256, 0, stream>>>(ww, wwb, (NH * KSZ * CD) / 4);

  // h1' = x @ w1^T + b1   (conv-layout bf16)
  gemm_bt<3, 0, 0><<<2048, 256, 0, stream>>>(xbt, w1b, b1, h1p, CD, E_DIM, 0, 8);
  // wt[b][h][t][k] = h1' @ ww^T + bw   (f32, N=496 guarded)
  gemm_bt<2, 1, 1><<<1024, 256, 0, stream>>>(h1p, wwb, bw, wt, NH * KSZ, CD, 0, 4);
  softmax31<<<2048, 256, 0, stream>>>(wt);
  dconv<<<8192, 256, 0, stream>>>(h1p, wt, zreg, convp);
  // h2' = conv' @ w2^T + b2   (bf16, rows m')
  gemm_bt<1, 0, 1><<<2048, 256, 0, stream>>>(convp, w2b, b2, h2p, E_DIM, CD, E_DIM, 8);
  ln_res<<<32768, 256, 0, stream>>>(x, h2p, out, gamma, beta);
}

// Round 5
// 497.419 us; speedup vs baseline: 1.7647x; 1.7647x over previous
//
#include <hip/hip_runtime.h>

#define T_DIM 2048
#define B_DIM 16
#define E_DIM 1024
#define CD    1024
#define NH    16
#define KSZ   31
#define M_DIM 32768
#define SLICE 131072            // 2048*64 elements per (b,h) slice
#define BSTRIDE 2097152         // 2048*1024 = 16*SLICE

typedef unsigned int u32;
typedef unsigned short u16;
typedef __attribute__((ext_vector_type(8))) __bf16 bf16x8;
typedef __attribute__((ext_vector_type(4))) float f32x4;
typedef __attribute__((ext_vector_type(4))) float fvec4;
typedef __attribute__((ext_vector_type(8))) unsigned short us8;
typedef __attribute__((ext_vector_type(4))) unsigned short us4;
typedef __attribute__((ext_vector_type(4))) unsigned int ui4;

__device__ __forceinline__ float bf2f(u16 u) {
  union { float f; u32 i; } c; c.i = ((u32)u) << 16; return c.f;
}
__device__ __forceinline__ u16 f2bf(float f) {
  union { float f; u32 i; } c; c.f = f;
  u32 u = c.i;
  u += 0x7fffu + ((u >> 16) & 1u);   // RNE
  return (u16)(u >> 16);
}

#define GLDS(gp, lp)                                                        \
  __builtin_amdgcn_global_load_lds(                                         \
      (__attribute__((address_space(1))) void*)(gp),                        \
      (__attribute__((address_space(3))) void*)(lp), 16, 0, 0)

// ---------------------------------------------------------------- zero scratch (4 KB)
__global__ __launch_bounds__(256) void zfill(u16* __restrict__ z) {
  ((ui4*)z)[threadIdx.x] = (ui4)(0u);
}

// ---------------------------------------------------------------- cvt f32->bf16 (weights)
__global__ __launch_bounds__(256) void cvt_f32_bf16(const float* __restrict__ src,
                                                    u16* __restrict__ dst, int n4) {
  int i = blockIdx.x * 256 + threadIdx.x;
  int stride = gridDim.x * 256;
  const fvec4* s4 = (const fvec4*)src;
  us4* d4 = (us4*)dst;
  for (; i < n4; i += stride) {
    fvec4 v = s4[i];
    us4 o;
    o[0] = f2bf(v[0]); o[1] = f2bf(v[1]); o[2] = f2bf(v[2]); o[3] = f2bf(v[3]);
    d4[i] = o;
  }
}

// ---------------------------------------------------------------- cvt + row-permute x: [t][b][e] f32 -> [b][t][e] bf16
__global__ __launch_bounds__(256) void cvt_x_tr(const float* __restrict__ x,
                                                u16* __restrict__ xbt) {
  int rr = blockIdx.x;           // t*16+b
  int t = rr >> 4, b = rr & 15;
  const fvec4* src = (const fvec4*)(x + (size_t)rr * E_DIM);
  us4* dst = (us4*)(xbt + ((size_t)b * T_DIM + t) * E_DIM);
  fvec4 v = src[threadIdx.x];
  us4 o;
  o[0] = f2bf(v[0]); o[1] = f2bf(v[1]); o[2] = f2bf(v[2]); o[3] = f2bf(v[3]);
  dst[threadIdx.x] = o;
}

// ---------------------------------------------------------------- bf16 MFMA GEMM (B^T layout), rows indexed m' = b*2048+t
// C[M,N] = A[M,K] * B[N,K]^T + bias.  128x128 tile, BK=32, 4 waves (2x2 of 64x64).
// A_CONV: 0 = row-major stride K; 1 = conv layout A[(b*16 + k/64)*SLICE + t*64 + k%64].
// OUT_MODE: 1 = bf16 row-major (ldc); 2 = wt[b][h][t][32] f32; 3 = conv-layout bf16.
template<int OUT_MODE, int GUARD_N, int A_CONV>
__global__ __launch_bounds__(256) void gemm_bt(
    const u16* __restrict__ A, const u16* __restrict__ B,
    const float* __restrict__ bias, void* __restrict__ Cout,
    int N, int K, int ldc, int ntn)
{
  constexpr int BK = 32;
  __shared__ u16 sA[128 * BK];
  __shared__ u16 sB[128 * BK];
  const int tid = threadIdx.x;
  const int lane = tid & 63;
  const int wid = tid >> 6;
  const int bm = (blockIdx.x / ntn) * 128;
  const int bn = (blockIdx.x % ntn) * 128;
  const int wr = (wid >> 1) * 64;
  const int wc = (wid & 1) * 64;

  const int srow = tid >> 2;            // 0..63
  const int skoff = (tid & 3) * 8;      // k element offset (0..24)
  const int rr0 = bm + srow, rr1 = bm + srow + 64;
  const u16 *pA0, *pA1;
  if (A_CONV) {
    pA0 = A + (size_t)(rr0 >> 11) * BSTRIDE + (size_t)(rr0 & 2047) * 64 + skoff;
    pA1 = A + (size_t)(rr1 >> 11) * BSTRIDE + (size_t)(rr1 & 2047) * 64 + skoff;
  } else {
    pA0 = A + (size_t)rr0 * K + skoff;
    pA1 = A + (size_t)rr1 * K + skoff;
  }
  int brow0 = bn + srow, brow1 = bn + srow + 64;
  if (GUARD_N) { brow0 = min(brow0, N - 1); brow1 = min(brow1, N - 1); }
  const u16* pB0 = B + (size_t)brow0 * K + skoff;
  const u16* pB1 = B + (size_t)brow1 * K + skoff;

  u16* lA0 = sA + wid * 512;            // wave-uniform LDS bases
  u16* lA1 = sA + 2048 + wid * 512;
  u16* lB0 = sB + wid * 512;
  u16* lB1 = sB + 2048 + wid * 512;

  f32x4 acc[4][4];
  #pragma unroll
  for (int i = 0; i < 4; i++)
    #pragma unroll
    for (int j = 0; j < 4; j++) acc[i][j] = (f32x4)(0.0f);

  const int fr = lane & 15;
  const int fk = (lane >> 4) * 8;

  for (int k0 = 0; k0 < K; k0 += BK) {
    const u16 *ga0, *ga1;
    if (A_CONV) {
      int ko = (k0 >> 6) * SLICE + (k0 & 32);
      ga0 = pA0 + ko; ga1 = pA1 + ko;
    } else {
      ga0 = pA0 + k0; ga1 = pA1 + k0;
    }
    __syncthreads();
    GLDS(ga0, lA0);
    GLDS(ga1, lA1);
    GLDS(pB0 + k0, lB0);
    GLDS(pB1 + k0, lB1);
    __syncthreads();
    bf16x8 aF[4], bF[4];
    #pragma unroll
    for (int m = 0; m < 4; m++)
      aF[m] = *(const bf16x8*)(sA + (wr + m * 16 + fr) * BK + fk);
    #pragma unroll
    for (int n = 0; n < 4; n++)
      bF[n] = *(const bf16x8*)(sB + (wc + n * 16 + fr) * BK + fk);
    #pragma unroll
    for (int m = 0; m < 4; m++)
      #pragma unroll
      for (int n = 0; n < 4; n++)
        acc[m][n] = __builtin_amdgcn_mfma_f32_16x16x32_bf16(aF[m], bF[n], acc[m][n], 0, 0, 0);
  }

  const int orow = bm + wr + (lane >> 4) * 4;   // C/D: col=lane&15, row=(lane>>4)*4+q
  const int ocol = bn + wc + fr;
  #pragma unroll
  for (int m = 0; m < 4; m++) {
    #pragma unroll
    for (int n = 0; n < 4; n++) {
      #pragma unroll
      for (int q = 0; q < 4; q++) {
        int row = orow + m * 16 + q;
        int col = ocol + n * 16;
        if (!GUARD_N || col < N) {
          float v = acc[m][n][q] + bias[col];
          if (OUT_MODE == 1) {
            ((u16*)Cout)[(size_t)row * ldc + col] = f2bf(v);
          } else if (OUT_MODE == 2) {
            int bb = row >> 11, t = row & 2047;
            int hh = col / 31, kk = col - hh * 31;      // compile-time magic div
            ((float*)Cout)[((size_t)((bb * NH + hh) * T_DIM + t)) * 32 + kk] = v;
          } else {                                       // 3: conv layout bf16
            int bb = row >> 11, t = row & 2047;
            ((u16*)Cout)[(size_t)((bb << 4) + (col >> 6)) * SLICE + (size_t)t * 64 + (col & 63)] = f2bf(v);
          }
        }
      }
    }
  }
}

// ---------------------------------------------------------------- softmax over K=31, in place on wt rows
__global__ __launch_bounds__(256) void softmax31(float* __restrict__ wt) {
  int idx = blockIdx.x * 256 + threadIdx.x;   // one row (b,h,t) per thread
  float* p = wt + (size_t)idx * 32;
  float v[KSZ];
  float mx = -1e30f;
  #pragma unroll
  for (int k = 0; k < KSZ; k++) { v[k] = p[k]; mx = fmaxf(mx, v[k]); }
  float s = 0.f;
  #pragma unroll
  for (int k = 0; k < KSZ; k++) { v[k] = __expf(v[k] - mx); s += v[k]; }
  float inv = 1.0f / s;
  #pragma unroll
  for (int k = 0; k < KSZ; k++) p[k] = v[k] * inv;
}

// ---------------------------------------------------------------- dynamic conv (conv-layout, traffic-exact)
// h1'[s][t][64], s=b*16+h. Block: 64 t of one slice. Thread: 8 ch x rows {tl, tl+32}.
// w staged in LDS (one contiguous 8 KB read); h staged via GLDS (1 KB/instr);
// stores are fully contiguous per instruction (byte offset = tid*16).
__global__ __launch_bounds__(256) void dconv(const u16* __restrict__ h1,
                                             const float* __restrict__ wt,
                                             const u16* __restrict__ zreg,
                                             u16* __restrict__ outc)
{
  constexpr int TT = 64, HALO = 30, SW = 33;
  int bid = blockIdx.x;
  int tt = bid & 31;            // T/64 = 32
  int s  = bid >> 5;            // b*16+h, 0..255
  int t0 = tt * TT;
  __shared__ u16 hl[96 * 64];   // 12 KB (rows t0-30 .. t0+65; 94,95 staged-unused)
  __shared__ float wl[TT * SW]; // 8.25 KB, stride 33 -> tl-groups on distinct banks
  int tid = threadIdx.x;

  const u16* slice = h1 + (size_t)s * SLICE;
  #pragma unroll
  for (int it = 0; it < 3; it++) {
    int c = it * 256 + tid;
    int row = t0 - HALO + (c >> 3);
    const u16* src = slice + (size_t)row * 64 + (c & 7) * 8;
    if (row < 0) src = zreg + (c & 7) * 8;      // zeroed scratch
    GLDS(src, hl + c * 8);
  }
  const float* wsrc = wt + ((size_t)s * T_DIM + t0) * 32;   // contiguous 8 KB
  #pragma unroll
  for (int it = 0; it < 2; it++) {
    int j = it * 1024 + tid * 4;        // flat f32 index, 16B-aligned chunks
    f32x4 v = *(const f32x4*)(wsrc + j);
    int row = j >> 5, col = j & 31;
    *(f32x4*)(&wl[row * SW + col]) = v;
  }
  __syncthreads();

  int rb = (tid & 7) * 8;           // channel sub-block
  int tl = tid >> 3;                // 0..31

  #pragma unroll
  for (int half = 0; half < 2; half++) {
    const int tb = tl + half * 32;
    const float* wp = wl + tb * SW;
    const u16* hb = hl + tb * 64 + rb;
    float acc[8];
    #pragma unroll
    for (int e = 0; e < 8; e++) acc[e] = 0.f;
    #pragma unroll
    for (int k = 0; k < KSZ; k++) {
      us8 hv = *(const us8*)(hb + k * 64);
      float w = wp[k];
      #pragma unroll
      for (int e = 0; e < 8; e++) acc[e] += w * bf2f(hv[e]);
    }
    us8 o;
    #pragma unroll
    for (int e = 0; e < 8; e++) o[e] = f2bf(acc[e]);
    // byte offset = half*4096 + tid*16: contiguous 4 KB span per instruction
    *(us8*)(outc + (size_t)s * SLICE + (size_t)(t0 + tb) * 64 + rb) = o;
  }
}

// ---------------------------------------------------------------- residual + LayerNorm
// h2'[m'][e] (m' = b*2048+t, bf16) + x[t*16+b][e] (f32) -> out[t*16+b][e] (f32)
__global__ __launch_bounds__(256) void ln_res(const float* __restrict__ x,
                                              const u16* __restrict__ hb,
                                              float* __restrict__ out,
                                              const float* __restrict__ gamma,
                                              const float* __restrict__ beta)
{
  int mp = blockIdx.x;                 // b*2048 + t
  int b = mp >> 11, t = mp & 2047;
  int xrow = t * 16 + b;
  const fvec4* xr = (const fvec4*)(x + (size_t)xrow * E_DIM);
  const us4* hr = (const us4*)(hb + (size_t)mp * E_DIM);
  fvec4* yr = (fvec4*)(out + (size_t)xrow * E_DIM);
  int tid = threadIdx.x;
  us4 hv = hr[tid];
  fvec4 xv = xr[tid];
  fvec4 s;
  #pragma unroll
  for (int e = 0; e < 4; e++) s[e] = xv[e] + bf2f(hv[e]);
  float sum = s[0] + s[1] + s[2] + s[3];
  float sq  = s[0]*s[0] + s[1]*s[1] + s[2]*s[2] + s[3]*s[3];
  #pragma unroll
  for (int off = 32; off >= 1; off >>= 1) {
    sum += __shfl_xor(sum, off, 64);
    sq  += __shfl_xor(sq, off, 64);
  }
  __shared__ float red[8];
  int lane = tid & 63, wid = tid >> 6;
  if (lane == 0) { red[wid] = sum; red[4 + wid] = sq; }
  __syncthreads();
  sum = red[0] + red[1] + red[2] + red[3];
  sq  = red[4] + red[5] + red[6] + red[7];
  float mean = sum * (1.0f / E_DIM);
  float var  = sq * (1.0f / E_DIM) - mean * mean;
  float rstd = rsqrtf(var + 1e-5f);
  fvec4 g = ((const fvec4*)gamma)[tid];
  fvec4 be = ((const fvec4*)beta)[tid];
  fvec4 o;
  #pragma unroll
  for (int e = 0; e < 4; e++) o[e] = (s[e] - mean) * rstd * g[e] + be[e];
  yr[tid] = o;
}

// ---------------------------------------------------------------- launcher
extern "C" void kernel_launch(void* const* d_in, const int* in_sizes, int n_in,
                              void* d_out, int out_size, void* d_ws, size_t ws_size,
                              hipStream_t stream)
{
  const float* x     = (const float*)d_in[0];
  const float* w1    = (const float*)d_in[1];
  const float* b1    = (const float*)d_in[2];
  const float* ww    = (const float*)d_in[3];
  const float* bw    = (const float*)d_in[4];
  const float* w2    = (const float*)d_in[5];
  const float* b2    = (const float*)d_in[6];
  const float* gamma = (const float*)d_in[7];
  const float* beta  = (const float*)d_in[8];
  float* out = (float*)d_out;

  char* ws = (char*)d_ws;
  u16*   xbt  = (u16*)(ws);                          // 64 MB  xb'[b][t][e]; reused as conv'
  u16*   h1p  = (u16*)(ws + ((size_t)64 << 20));     // 64 MB  h1'[s][t][64]; reused as h2'
  float* wt   = (float*)(ws + ((size_t)128 << 20));  // 64 MB  wt[b][h][t][32] f32
  u16*   w1b  = (u16*)(ws + ((size_t)192 << 20));    // 2 MB
  u16*   w2b  = (u16*)(ws + ((size_t)194 << 20));    // 2 MB
  u16*   wwb  = (u16*)(ws + ((size_t)196 << 20));    // ~1 MB
  u16*   zreg = (u16*)(ws + ((size_t)198 << 20));    // 4 KB zeroed
  u16*   convp = xbt;
  u16*   h2p  = h1p;

  zfill<<<1, 256, 0, stream>>>(zreg);
  cvt_x_tr<<<32768, 256, 0, stream>>>(x, xbt);
  cvt_f32_bf16<<<1024, 256, 0, stream>>>(w1, w1b, (CD * E_DIM) / 4);
  cvt_f32_bf16<<<1024, 256, 0, stream>>>(w2, w2b, (E_DIM * CD) / 4);
  cvt_f32_bf16<<<512,  256, 0, stream>>>(ww, wwb, (NH * KSZ * CD) / 4);

  // h1' = x @ w1^T + b1   (conv-layout bf16)
  gemm_bt<3, 0, 0><<<2048, 256, 0, stream>>>(xbt, w1b, b1, h1p, CD, E_DIM, 0, 8);
  // wt[b][h][t][k] = h1' @ ww^T + bw   (f32, N=496 guarded)
  gemm_bt<2, 1, 1><<<1024, 256, 0, stream>>>(h1p, wwb, bw, wt, NH * KSZ, CD, 0, 4);
  softmax31<<<2048, 256, 0, stream>>>(wt);
  dconv<<<8192, 256, 0, stream>>>(h1p, wt, zreg, convp);
  // h2' = conv' @ w2^T + b2   (bf16, rows m')
  gemm_bt<1, 0, 1><<<2048, 256, 0, stream>>>(convp, w2b, b2, h2p, E_DIM, CD, E_DIM, 8);
  ln_res<<<32768, 256, 0, stream>>>(x, h2p, out, gamma, beta);
}

// Round 6
// 460.474 us; speedup vs baseline: 1.9063x; 1.0802x over previous
//
#include <hip/hip_runtime.h>

#define T_DIM 2048
#define B_DIM 16
#define E_DIM 1024
#define CD    1024
#define NH    16
#define KSZ   31
#define M_DIM 32768
#define SLICE 131072            // 2048*64 elements per (b,h) slice
#define BSTRIDE 2097152         // 2048*1024 = 16*SLICE

typedef unsigned int u32;
typedef unsigned short u16;
typedef __attribute__((ext_vector_type(8))) __bf16 bf16x8;
typedef __attribute__((ext_vector_type(4))) float f32x4;
typedef __attribute__((ext_vector_type(4))) float fvec4;
typedef __attribute__((ext_vector_type(8))) unsigned short us8;
typedef __attribute__((ext_vector_type(4))) unsigned short us4;
typedef __attribute__((ext_vector_type(4))) unsigned int ui4;

__device__ __forceinline__ float bf2f(u16 u) {
  union { float f; u32 i; } c; c.i = ((u32)u) << 16; return c.f;
}
__device__ __forceinline__ u16 f2bf(float f) {
  union { float f; u32 i; } c; c.f = f;
  u32 u = c.i;
  u += 0x7fffu + ((u >> 16) & 1u);   // RNE
  return (u16)(u >> 16);
}

#define GLDS(gp, lp)                                                        \
  __builtin_amdgcn_global_load_lds(                                         \
      (__attribute__((address_space(1))) void*)(gp),                        \
      (__attribute__((address_space(3))) void*)(lp), 16, 0, 0)

// ---------------------------------------------------------------- zero scratch (4 KB)
__global__ __launch_bounds__(256) void zfill(u16* __restrict__ z) {
  ((ui4*)z)[threadIdx.x] = (ui4)(0u);
}

// ---------------------------------------------------------------- cvt f32->bf16 (weights)
__global__ __launch_bounds__(256) void cvt_f32_bf16(const float* __restrict__ src,
                                                    u16* __restrict__ dst, int n4) {
  int i = blockIdx.x * 256 + threadIdx.x;
  int stride = gridDim.x * 256;
  const fvec4* s4 = (const fvec4*)src;
  us4* d4 = (us4*)dst;
  for (; i < n4; i += stride) {
    fvec4 v = s4[i];
    us4 o;
    o[0] = f2bf(v[0]); o[1] = f2bf(v[1]); o[2] = f2bf(v[2]); o[3] = f2bf(v[3]);
    d4[i] = o;
  }
}

// ---------------------------------------------------------------- cvt + row-permute x: [t][b][e] f32 -> [b][t][e] bf16
__global__ __launch_bounds__(256) void cvt_x_tr(const float* __restrict__ x,
                                                u16* __restrict__ xbt) {
  int rr = blockIdx.x;           // t*16+b
  int t = rr >> 4, b = rr & 15;
  const fvec4* src = (const fvec4*)(x + (size_t)rr * E_DIM);
  us4* dst = (us4*)(xbt + ((size_t)b * T_DIM + t) * E_DIM);
  fvec4 v = src[threadIdx.x];
  us4 o;
  o[0] = f2bf(v[0]); o[1] = f2bf(v[1]); o[2] = f2bf(v[2]); o[3] = f2bf(v[3]);
  dst[threadIdx.x] = o;
}

// ---------------------------------------------------------------- bf16 MFMA GEMM (B^T layout), rows indexed m' = b*2048+t
// C[M,N] = A[M,K] * B[N,K]^T + bias.  128x128 tile, BK=32, 4 waves (2x2 of 64x64).
// XCD-chunk swizzle (T1) + double-buffered LDS with stage-ahead (T3 minimum-2-phase).
// A_CONV: 0 = row-major stride K; 1 = conv layout A[(b*16 + k/64)*SLICE + t*64 + k%64].
// OUT_MODE: 1 = bf16 row-major (ldc); 2 = wt[b][h][t][32] f32; 3 = conv-layout bf16.
template<int OUT_MODE, int GUARD_N, int A_CONV>
__global__ __launch_bounds__(256) void gemm_bt(
    const u16* __restrict__ A, const u16* __restrict__ B,
    const float* __restrict__ bias, void* __restrict__ Cout,
    int N, int K, int ldc, int ntn)
{
  constexpr int BK = 32;
  __shared__ u16 sA[2 * 128 * BK];     // 16 KB x2 buffers (A)
  __shared__ u16 sB[2 * 128 * BK];     // 16 KB x2 buffers (B)
  const int tid = threadIdx.x;
  const int lane = tid & 63;
  const int wid = tid >> 6;
  // T1: bijective XCD chunk swizzle (gridDim.x % 8 == 0 for all our launches).
  const int swz = (blockIdx.x & 7) * (gridDim.x >> 3) + (blockIdx.x >> 3);
  const int bm = (swz / ntn) * 128;
  const int bn = (swz % ntn) * 128;
  const int wr = (wid >> 1) * 64;
  const int wc = (wid & 1) * 64;

  const int srow = tid >> 2;            // 0..63
  const int skoff = (tid & 3) * 8;      // k element offset (0..24)
  const int rr0 = bm + srow, rr1 = bm + srow + 64;
  const u16 *pA0, *pA1;
  if (A_CONV) {
    pA0 = A + (size_t)(rr0 >> 11) * BSTRIDE + (size_t)(rr0 & 2047) * 64 + skoff;
    pA1 = A + (size_t)(rr1 >> 11) * BSTRIDE + (size_t)(rr1 & 2047) * 64 + skoff;
  } else {
    pA0 = A + (size_t)rr0 * K + skoff;
    pA1 = A + (size_t)rr1 * K + skoff;
  }
  int brow0 = bn + srow, brow1 = bn + srow + 64;
  if (GUARD_N) { brow0 = min(brow0, N - 1); brow1 = min(brow1, N - 1); }
  const u16* pB0 = B + (size_t)brow0 * K + skoff;
  const u16* pB1 = B + (size_t)brow1 * K + skoff;

  auto stage = [&](int buf, int k0) {
    const u16 *ga0, *ga1;
    if (A_CONV) {
      int ko = (k0 >> 6) * SLICE + (k0 & 32);
      ga0 = pA0 + ko; ga1 = pA1 + ko;
    } else {
      ga0 = pA0 + k0; ga1 = pA1 + k0;
    }
    u16* dA = sA + buf * 4096 + wid * 512;     // wave-uniform LDS bases
    u16* dB = sB + buf * 4096 + wid * 512;
    GLDS(ga0, dA);
    GLDS(ga1, dA + 2048);
    GLDS(pB0 + k0, dB);
    GLDS(pB1 + k0, dB + 2048);
  };

  f32x4 acc[4][4];
  #pragma unroll
  for (int i = 0; i < 4; i++)
    #pragma unroll
    for (int j = 0; j < 4; j++) acc[i][j] = (f32x4)(0.0f);

  const int fr = lane & 15;
  const int fk = (lane >> 4) * 8;

  stage(0, 0);
  __syncthreads();                       // drains vmcnt(0): buf0 ready
  for (int k0 = 0; k0 < K; k0 += BK) {
    const int cur = (k0 >> 5) & 1;
    if (k0 + BK < K) stage(cur ^ 1, k0 + BK);   // prefetch next tile; in flight during MFMA
    const u16* bA = sA + cur * 4096;
    const u16* bBp = sB + cur * 4096;
    bf16x8 aF[4], bF[4];
    #pragma unroll
    for (int m = 0; m < 4; m++)
      aF[m] = *(const bf16x8*)(bA + (wr + m * 16 + fr) * BK + fk);
    #pragma unroll
    for (int n = 0; n < 4; n++)
      bF[n] = *(const bf16x8*)(bBp + (wc + n * 16 + fr) * BK + fk);
    #pragma unroll
    for (int m = 0; m < 4; m++)
      #pragma unroll
      for (int n = 0; n < 4; n++)
        acc[m][n] = __builtin_amdgcn_mfma_f32_16x16x32_bf16(aF[m], bF[n], acc[m][n], 0, 0, 0);
    __syncthreads();                     // drains staging loads + ds reads; one barrier/K-step
  }

  const int orow = bm + wr + (lane >> 4) * 4;   // C/D: col=lane&15, row=(lane>>4)*4+q
  const int ocol = bn + wc + fr;
  #pragma unroll
  for (int m = 0; m < 4; m++) {
    #pragma unroll
    for (int n = 0; n < 4; n++) {
      #pragma unroll
      for (int q = 0; q < 4; q++) {
        int row = orow + m * 16 + q;
        int col = ocol + n * 16;
        if (!GUARD_N || col < N) {
          float v = acc[m][n][q] + bias[col];
          if (OUT_MODE == 1) {
            ((u16*)Cout)[(size_t)row * ldc + col] = f2bf(v);
          } else if (OUT_MODE == 2) {
            int bb = row >> 11, t = row & 2047;
            int hh = col / 31, kk = col - hh * 31;      // compile-time magic div
            ((float*)Cout)[((size_t)((bb * NH + hh) * T_DIM + t)) * 32 + kk] = v;
          } else {                                       // 3: conv layout bf16
            int bb = row >> 11, t = row & 2047;
            ((u16*)Cout)[(size_t)((bb << 4) + (col >> 6)) * SLICE + (size_t)t * 64 + (col & 63)] = f2bf(v);
          }
        }
      }
    }
  }
}

// ---------------------------------------------------------------- softmax over K=31, in place on wt rows
__global__ __launch_bounds__(256) void softmax31(float* __restrict__ wt) {
  int idx = blockIdx.x * 256 + threadIdx.x;   // one row (b,h,t) per thread
  float* p = wt + (size_t)idx * 32;
  float v[KSZ];
  float mx = -1e30f;
  #pragma unroll
  for (int k = 0; k < KSZ; k++) { v[k] = p[k]; mx = fmaxf(mx, v[k]); }
  float s = 0.f;
  #pragma unroll
  for (int k = 0; k < KSZ; k++) { v[k] = __expf(v[k] - mx); s += v[k]; }
  float inv = 1.0f / s;
  #pragma unroll
  for (int k = 0; k < KSZ; k++) p[k] = v[k] * inv;
}

// ---------------------------------------------------------------- dynamic conv (conv-layout, traffic-exact)
// h1'[s][t][64], s=b*16+h. Block: 64 t of one slice. Thread: 8 ch x rows {tl, tl+32}.
// w staged in LDS (one contiguous 8 KB read); h staged via GLDS (1 KB/instr);
// stores are fully contiguous per instruction (byte offset = tid*16).
__global__ __launch_bounds__(256) void dconv(const u16* __restrict__ h1,
                                             const float* __restrict__ wt,
                                             const u16* __restrict__ zreg,
                                             u16* __restrict__ outc)
{
  constexpr int TT = 64, HALO = 30, SW = 33;
  int bid = blockIdx.x;
  int tt = bid & 31;            // T/64 = 32
  int s  = bid >> 5;            // b*16+h, 0..255
  int t0 = tt * TT;
  __shared__ u16 hl[96 * 64];   // 12 KB (rows t0-30 .. t0+65; 94,95 staged-unused)
  __shared__ float wl[TT * SW]; // 8.25 KB, stride 33 -> tl-groups on distinct banks
  int tid = threadIdx.x;

  const u16* slice = h1 + (size_t)s * SLICE;
  #pragma unroll
  for (int it = 0; it < 3; it++) {
    int c = it * 256 + tid;
    int row = t0 - HALO + (c >> 3);
    const u16* src = slice + (size_t)row * 64 + (c & 7) * 8;
    if (row < 0) src = zreg + (c & 7) * 8;      // zeroed scratch
    GLDS(src, hl + c * 8);
  }
  const float* wsrc = wt + ((size_t)s * T_DIM + t0) * 32;   // contiguous 8 KB
  #pragma unroll
  for (int it = 0; it < 2; it++) {
    int j = it * 1024 + tid * 4;        // flat f32 index, 16B-aligned chunks
    f32x4 v = *(const f32x4*)(wsrc + j);
    int row = j >> 5, col = j & 31;
    *(f32x4*)(&wl[row * SW + col]) = v;
  }
  __syncthreads();

  int rb = (tid & 7) * 8;           // channel sub-block
  int tl = tid >> 3;                // 0..31

  #pragma unroll
  for (int half = 0; half < 2; half++) {
    const int tb = tl + half * 32;
    const float* wp = wl + tb * SW;
    const u16* hb = hl + tb * 64 + rb;
    float acc[8];
    #pragma unroll
    for (int e = 0; e < 8; e++) acc[e] = 0.f;
    #pragma unroll
    for (int k = 0; k < KSZ; k++) {
      us8 hv = *(const us8*)(hb + k * 64);
      float w = wp[k];
      #pragma unroll
      for (int e = 0; e < 8; e++) acc[e] += w * bf2f(hv[e]);
    }
    us8 o;
    #pragma unroll
    for (int e = 0; e < 8; e++) o[e] = f2bf(acc[e]);
    // byte offset = half*4096 + tid*16: contiguous 4 KB span per instruction
    *(us8*)(outc + (size_t)s * SLICE + (size_t)(t0 + tb) * 64 + rb) = o;
  }
}

// ---------------------------------------------------------------- residual + LayerNorm
// h2'[m'][e] (m' = b*2048+t, bf16) + x[t*16+b][e] (f32) -> out[t*16+b][e] (f32)
__global__ __launch_bounds__(256) void ln_res(const float* __restrict__ x,
                                              const u16* __restrict__ hb,
                                              float* __restrict__ out,
                                              const float* __restrict__ gamma,
                                              const float* __restrict__ beta)
{
  int mp = blockIdx.x;                 // b*2048 + t
  int b = mp >> 11, t = mp & 2047;
  int xrow = t * 16 + b;
  const fvec4* xr = (const fvec4*)(x + (size_t)xrow * E_DIM);
  const us4* hr = (const us4*)(hb + (size_t)mp * E_DIM);
  fvec4* yr = (fvec4*)(out + (size_t)xrow * E_DIM);
  int tid = threadIdx.x;
  us4 hv = hr[tid];
  fvec4 xv = xr[tid];
  fvec4 s;
  #pragma unroll
  for (int e = 0; e < 4; e++) s[e] = xv[e] + bf2f(hv[e]);
  float sum = s[0] + s[1] + s[2] + s[3];
  float sq  = s[0]*s[0] + s[1]*s[1] + s[2]*s[2] + s[3]*s[3];
  #pragma unroll
  for (int off = 32; off >= 1; off >>= 1) {
    sum += __shfl_xor(sum, off, 64);
    sq  += __shfl_xor(sq, off, 64);
  }
  __shared__ float red[8];
  int lane = tid & 63, wid = tid >> 6;
  if (lane == 0) { red[wid] = sum; red[4 + wid] = sq; }
  __syncthreads();
  sum = red[0] + red[1] + red[2] + red[3];
  sq  = red[4] + red[5] + red[6] + red[7];
  float mean = sum * (1.0f / E_DIM);
  float var  = sq * (1.0f / E_DIM) - mean * mean;
  float rstd = rsqrtf(var + 1e-5f);
  fvec4 g = ((const fvec4*)gamma)[tid];
  fvec4 be = ((const fvec4*)beta)[tid];
  fvec4 o;
  #pragma unroll
  for (int e = 0; e < 4; e++) o[e] = (s[e] - mean) * rstd * g[e] + be[e];
  yr[tid] = o;
}

// ---------------------------------------------------------------- launcher
extern "C" void kernel_launch(void* const* d_in, const int* in_sizes, int n_in,
                              void* d_out, int out_size, void* d_ws, size_t ws_size,
                              hipStream_t stream)
{
  const float* x     = (const float*)d_in[0];
  const float* w1    = (const float*)d_in[1];
  const float* b1    = (const float*)d_in[2];
  const float* ww    = (const float*)d_in[3];
  const float* bw    = (const float*)d_in[4];
  const float* w2    = (const float*)d_in[5];
  const float* b2    = (const float*)d_in[6];
  const float* gamma = (const float*)d_in[7];
  const float* beta  = (const float*)d_in[8];
  float* out = (float*)d_out;

  char* ws = (char*)d_ws;
  u16*   xbt  = (u16*)(ws);                          // 64 MB  xb'[b][t][e]; reused as conv'
  u16*   h1p  = (u16*)(ws + ((size_t)64 << 20));     // 64 MB  h1'[s][t][64]; reused as h2'
  float* wt   = (float*)(ws + ((size_t)128 << 20));  // 64 MB  wt[b][h][t][32] f32
  u16*   w1b  = (u16*)(ws + ((size_t)192 << 20));    // 2 MB
  u16*   w2b  = (u16*)(ws + ((size_t)194 << 20));    // 2 MB
  u16*   wwb  = (u16*)(ws + ((size_t)196 << 20));    // ~1 MB
  u16*   zreg = (u16*)(ws + ((size_t)198 << 20));    // 4 KB zeroed
  u16*   convp = xbt;
  u16*   h2p  = h1p;

  zfill<<<1, 256, 0, stream>>>(zreg);
  cvt_x_tr<<<32768, 256, 0, stream>>>(x, xbt);
  cvt_f32_bf16<<<1024, 256, 0, stream>>>(w1, w1b, (CD * E_DIM) / 4);
  cvt_f32_bf16<<<1024, 256, 0, stream>>>(w2, w2b, (E_DIM * CD) / 4);
  cvt_f32_bf16<<<512,  256, 0, stream>>>(ww, wwb, (NH * KSZ * CD) / 4);

  // h1' = x @ w1^T + b1   (conv-layout bf16)
  gemm_bt<3, 0, 0><<<2048, 256, 0, stream>>>(xbt, w1b, b1, h1p, CD, E_DIM, 0, 8);
  // wt[b][h][t][k] = h1' @ ww^T + bw   (f32, N=496 guarded)
  gemm_bt<2, 1, 1><<<1024, 256, 0, stream>>>(h1p, wwb, bw, wt, NH * KSZ, CD, 0, 4);
  softmax31<<<2048, 256, 0, stream>>>(wt);
  dconv<<<8192, 256, 0, stream>>>(h1p, wt, zreg, convp);
  // h2' = conv' @ w2^T + b2   (bf16, rows m')
  gemm_bt<1, 0, 1><<<2048, 256, 0, stream>>>(convp, w2b, b2, h2p, E_DIM, CD, E_DIM, 8);
  ln_res<<<32768, 256, 0, stream>>>(x, h2p, out, gamma, beta);
}

// Round 7
// 424.113 us; speedup vs baseline: 2.0697x; 1.0857x over previous
//
#include <hip/hip_runtime.h>

#define T_DIM 2048
#define B_DIM 16
#define E_DIM 1024
#define CD    1024
#define NH    16
#define KSZ   31
#define M_DIM 32768
#define SLICE 131072            // 2048*64 elements per (b,h) slice
#define BSTRIDE 2097152         // 2048*1024 = 16*SLICE

typedef unsigned int u32;
typedef unsigned short u16;
typedef __attribute__((ext_vector_type(8))) __bf16 bf16x8;
typedef __attribute__((ext_vector_type(4))) float f32x4;
typedef __attribute__((ext_vector_type(4))) float fvec4;
typedef __attribute__((ext_vector_type(8))) unsigned short us8;
typedef __attribute__((ext_vector_type(4))) unsigned short us4;
typedef __attribute__((ext_vector_type(4))) unsigned int ui4;

__device__ __forceinline__ float bf2f(u16 u) {
  union { float f; u32 i; } c; c.i = ((u32)u) << 16; return c.f;
}
__device__ __forceinline__ u16 f2bf(float f) {
  union { float f; u32 i; } c; c.f = f;
  u32 u = c.i;
  u += 0x7fffu + ((u >> 16) & 1u);   // RNE
  return (u16)(u >> 16);
}

#define GLDS(gp, lp)                                                        \
  __builtin_amdgcn_global_load_lds(                                         \
      (__attribute__((address_space(1))) void*)(gp),                        \
      (__attribute__((address_space(3))) void*)(lp), 16, 0, 0)

// ---------------------------------------------------------------- zero scratch (4 KB)
__global__ __launch_bounds__(256) void zfill(u16* __restrict__ z) {
  ((ui4*)z)[threadIdx.x] = (ui4)(0u);
}

// ---------------------------------------------------------------- cvt f32->bf16 (weights)
__global__ __launch_bounds__(256) void cvt_f32_bf16(const float* __restrict__ src,
                                                    u16* __restrict__ dst, int n4) {
  int i = blockIdx.x * 256 + threadIdx.x;
  int stride = gridDim.x * 256;
  const fvec4* s4 = (const fvec4*)src;
  us4* d4 = (us4*)dst;
  for (; i < n4; i += stride) {
    fvec4 v = s4[i];
    us4 o;
    o[0] = f2bf(v[0]); o[1] = f2bf(v[1]); o[2] = f2bf(v[2]); o[3] = f2bf(v[3]);
    d4[i] = o;
  }
}

// ---------------------------------------------------------------- cvt + row-permute x: [t][b][e] f32 -> [b][t][e] bf16
__global__ __launch_bounds__(256) void cvt_x_tr(const float* __restrict__ x,
                                                u16* __restrict__ xbt) {
  int rr = blockIdx.x;           // t*16+b
  int t = rr >> 4, b = rr & 15;
  const fvec4* src = (const fvec4*)(x + (size_t)rr * E_DIM);
  us4* dst = (us4*)(xbt + ((size_t)b * T_DIM + t) * E_DIM);
  fvec4 v = src[threadIdx.x];
  us4 o;
  o[0] = f2bf(v[0]); o[1] = f2bf(v[1]); o[2] = f2bf(v[2]); o[3] = f2bf(v[3]);
  dst[threadIdx.x] = o;
}

// ---------------------------------------------------------------- 256x256 8-phase bf16 MFMA GEMM (B^T layout)
// C[M,N] = A[M,K]*B[N,K]^T + bias. BK=64, 512 threads = 8 waves (2M x 4N),
// per-wave 128x64 output. T1 XCD swizzle + T2 LDS XOR swizzle + T3/T4 phased
// schedule with front-loaded staging (boundary vmcnt(0) waits ~4-phase-old loads)
// + T5 setprio. Raw s_barrier (no __syncthreads -> no compiler vmcnt drain).
// A_CONV: 0 = row-major stride K; 1 = conv layout. OUT_MODE: 1 bf16 ldc; 2 wt; 3 conv.
template<int OUT_MODE, int GUARD_N, int A_CONV>
__global__ __launch_bounds__(512, 2) void gemm256(
    const u16* __restrict__ A, const u16* __restrict__ B,
    const float* __restrict__ bias, void* __restrict__ Cout,
    int N, int K, int ldc, int ntn)
{
  __shared__ u16 sA[2][256 * 64];    // 32 KB per buf
  __shared__ u16 sB[2][256 * 64];    // total 128 KB
  const int tid = threadIdx.x;
  const int lane = tid & 63;
  const int wid = tid >> 6;          // 0..7
  const int wr = wid >> 2;           // M half
  const int wc = wid & 3;            // N quarter

  const int swz = (blockIdx.x & 7) * (gridDim.x >> 3) + (blockIdx.x >> 3);
  const int bm = (swz / ntn) * 256;
  const int bn = (swz % ntn) * 256;

  // staging: statement st covers tile rows [st*64, st*64+64); thread -> (row, 16B chunk)
  const int srow = tid >> 3;              // 0..63
  const int scol = (tid & 7) * 8;         // u16 col (16B chunks)
  const int scols = scol ^ ((srow & 7) << 3);   // inverse-swizzled global col

  const u16* gA[4];
  #pragma unroll
  for (int st = 0; st < 4; st++) {
    int rr = bm + st * 64 + srow;
    if (A_CONV)
      gA[st] = A + (size_t)(rr >> 11) * BSTRIDE + (size_t)(rr & 2047) * 64 + scols;
    else
      gA[st] = A + (size_t)rr * K + scols;
  }
  const u16* gB[4];
  #pragma unroll
  for (int st = 0; st < 4; st++) {
    int br = bn + st * 64 + srow;
    if (GUARD_N) br = min(br, N - 1);
    gB[st] = B + (size_t)br * K + scols;
  }
  const int sdst = (tid >> 3) * 64 + scol;   // (srow)*64 + scol ; add st*4096

  f32x4 acc[8][4];
  #pragma unroll
  for (int i = 0; i < 8; i++)
    #pragma unroll
    for (int j = 0; j < 4; j++) acc[i][j] = (f32x4)(0.0f);

  const int fr = lane & 15;
  const int g8 = (lane >> 4) * 8;          // u16 k-offset within 32-k half
  const int sx = (fr & 7) << 3;            // read-side swizzle (u16)

  const int NT = K >> 6;
  int buf = 0;

  // prologue: stage K-tile 0
  #pragma unroll
  for (int st = 0; st < 4; st++) GLDS(gA[st], &sA[0][st * 4096 + sdst]);
  #pragma unroll
  for (int st = 0; st < 4; st++) GLDS(gB[st], &sB[0][st * 4096 + sdst]);
  asm volatile("s_waitcnt vmcnt(0)" ::: "memory");
  __builtin_amdgcn_s_barrier();

  for (int kt = 0; kt < NT; kt++) {
    // ---------- phase 0: read all B frags + A m0,m1; front-load stage(kt+1); 16 MFMA
    bf16x8 bF[4][2];
    #pragma unroll
    for (int n = 0; n < 4; n++)
      #pragma unroll
      for (int kh = 0; kh < 2; kh++) {
        int row = wc * 64 + n * 16 + fr;
        bF[n][kh] = *(const bf16x8*)&sB[buf][row * 64 + ((kh * 32 + g8) ^ sx)];
      }
    bf16x8 aF[2][2];
    #pragma unroll
    for (int mi = 0; mi < 2; mi++)
      #pragma unroll
      for (int kh = 0; kh < 2; kh++) {
        int row = wr * 128 + mi * 16 + fr;
        aF[mi][kh] = *(const bf16x8*)&sA[buf][row * 64 + ((kh * 32 + g8) ^ sx)];
      }
    if (kt + 1 < NT) {
      const size_t koA = A_CONV ? (size_t)(kt + 1) * SLICE : (size_t)(kt + 1) * 64;
      const size_t koB = (size_t)(kt + 1) * 64;
      u16* dA = &sA[buf ^ 1][0];
      u16* dB = &sB[buf ^ 1][0];
      #pragma unroll
      for (int st = 0; st < 4; st++) GLDS(gA[st] + koA, dA + st * 4096 + sdst);
      #pragma unroll
      for (int st = 0; st < 4; st++) GLDS(gB[st] + koB, dB + st * 4096 + sdst);
    }
    __builtin_amdgcn_s_barrier();
    asm volatile("s_waitcnt lgkmcnt(0)" ::: "memory");
    __builtin_amdgcn_sched_barrier(0);
    __builtin_amdgcn_s_setprio(1);
    #pragma unroll
    for (int mi = 0; mi < 2; mi++)
      #pragma unroll
      for (int n = 0; n < 4; n++)
        #pragma unroll
        for (int kh = 0; kh < 2; kh++)
          acc[mi][n] = __builtin_amdgcn_mfma_f32_16x16x32_bf16(aF[mi][kh], bF[n][kh], acc[mi][n], 0, 0, 0);
    __builtin_amdgcn_s_setprio(0);
    __builtin_amdgcn_sched_barrier(0);
    __builtin_amdgcn_s_barrier();

    // ---------- phases 1..3: A m=2p,2p+1; 16 MFMA each
    #pragma unroll
    for (int p = 1; p < 4; p++) {
      bf16x8 aG[2][2];
      #pragma unroll
      for (int mi = 0; mi < 2; mi++)
        #pragma unroll
        for (int kh = 0; kh < 2; kh++) {
          int row = wr * 128 + (2 * p + mi) * 16 + fr;
          aG[mi][kh] = *(const bf16x8*)&sA[buf][row * 64 + ((kh * 32 + g8) ^ sx)];
        }
      __builtin_amdgcn_s_barrier();
      asm volatile("s_waitcnt lgkmcnt(0)" ::: "memory");
      __builtin_amdgcn_sched_barrier(0);
      __builtin_amdgcn_s_setprio(1);
      #pragma unroll
      for (int mi = 0; mi < 2; mi++)
        #pragma unroll
        for (int n = 0; n < 4; n++)
          #pragma unroll
          for (int kh = 0; kh < 2; kh++)
            acc[2 * p + mi][n] = __builtin_amdgcn_mfma_f32_16x16x32_bf16(aG[mi][kh], bF[n][kh], acc[2 * p + mi][n], 0, 0, 0);
      __builtin_amdgcn_s_setprio(0);
      __builtin_amdgcn_sched_barrier(0);
      if (p < 3) {
        __builtin_amdgcn_s_barrier();
      } else {
        // K-tile boundary: loads for kt+1 are ~4 phases old -> near-zero wait
        asm volatile("s_waitcnt vmcnt(0)" ::: "memory");
        __builtin_amdgcn_s_barrier();
      }
    }
    buf ^= 1;
  }

  const int orow0 = bm + wr * 128 + (lane >> 4) * 4;   // C/D: col=lane&15, row=(lane>>4)*4+q
  const int ocol0 = bn + wc * 64 + fr;
  #pragma unroll
  for (int m = 0; m < 8; m++) {
    #pragma unroll
    for (int n = 0; n < 4; n++) {
      #pragma unroll
      for (int q = 0; q < 4; q++) {
        int row = orow0 + m * 16 + q;
        int col = ocol0 + n * 16;
        if (!GUARD_N || col < N) {
          float v = acc[m][n][q] + bias[col];
          if (OUT_MODE == 1) {
            ((u16*)Cout)[(size_t)row * ldc + col] = f2bf(v);
          } else if (OUT_MODE == 2) {
            int bb = row >> 11, t = row & 2047;
            int hh = col / 31, kk = col - hh * 31;      // compile-time magic div
            ((float*)Cout)[((size_t)((bb * NH + hh) * T_DIM + t)) * 32 + kk] = v;
          } else {                                       // 3: conv layout bf16
            int bb = row >> 11, t = row & 2047;
            ((u16*)Cout)[(size_t)((bb << 4) + (col >> 6)) * SLICE + (size_t)t * 64 + (col & 63)] = f2bf(v);
          }
        }
      }
    }
  }
}

// ---------------------------------------------------------------- softmax over K=31, in place on wt rows
__global__ __launch_bounds__(256) void softmax31(float* __restrict__ wt) {
  int idx = blockIdx.x * 256 + threadIdx.x;   // one row (b,h,t) per thread
  float* p = wt + (size_t)idx * 32;
  float v[KSZ];
  float mx = -1e30f;
  #pragma unroll
  for (int k = 0; k < KSZ; k++) { v[k] = p[k]; mx = fmaxf(mx, v[k]); }
  float s = 0.f;
  #pragma unroll
  for (int k = 0; k < KSZ; k++) { v[k] = __expf(v[k] - mx); s += v[k]; }
  float inv = 1.0f / s;
  #pragma unroll
  for (int k = 0; k < KSZ; k++) p[k] = v[k] * inv;
}

// ---------------------------------------------------------------- dynamic conv (conv-layout, traffic-exact)
__global__ __launch_bounds__(256) void dconv(const u16* __restrict__ h1,
                                             const float* __restrict__ wt,
                                             const u16* __restrict__ zreg,
                                             u16* __restrict__ outc)
{
  constexpr int TT = 64, HALO = 30, SW = 33;
  int bid = blockIdx.x;
  int tt = bid & 31;            // T/64 = 32
  int s  = bid >> 5;            // b*16+h, 0..255
  int t0 = tt * TT;
  __shared__ u16 hl[96 * 64];   // 12 KB
  __shared__ float wl[TT * SW]; // 8.25 KB
  int tid = threadIdx.x;

  const u16* slice = h1 + (size_t)s * SLICE;
  #pragma unroll
  for (int it = 0; it < 3; it++) {
    int c = it * 256 + tid;
    int row = t0 - HALO + (c >> 3);
    const u16* src = slice + (size_t)row * 64 + (c & 7) * 8;
    if (row < 0) src = zreg + (c & 7) * 8;      // zeroed scratch
    GLDS(src, hl + c * 8);
  }
  const float* wsrc = wt + ((size_t)s * T_DIM + t0) * 32;   // contiguous 8 KB
  #pragma unroll
  for (int it = 0; it < 2; it++) {
    int j = it * 1024 + tid * 4;
    f32x4 v = *(const f32x4*)(wsrc + j);
    int row = j >> 5, col = j & 31;
    *(f32x4*)(&wl[row * SW + col]) = v;
  }
  __syncthreads();

  int rb = (tid & 7) * 8;           // channel sub-block
  int tl = tid >> 3;                // 0..31

  #pragma unroll
  for (int half = 0; half < 2; half++) {
    const int tb = tl + half * 32;
    const float* wp = wl + tb * SW;
    const u16* hb = hl + tb * 64 + rb;
    float acc[8];
    #pragma unroll
    for (int e = 0; e < 8; e++) acc[e] = 0.f;
    #pragma unroll
    for (int k = 0; k < KSZ; k++) {
      us8 hv = *(const us8*)(hb + k * 64);
      float w = wp[k];
      #pragma unroll
      for (int e = 0; e < 8; e++) acc[e] += w * bf2f(hv[e]);
    }
    us8 o;
    #pragma unroll
    for (int e = 0; e < 8; e++) o[e] = f2bf(acc[e]);
    *(us8*)(outc + (size_t)s * SLICE + (size_t)(t0 + tb) * 64 + rb) = o;
  }
}

// ---------------------------------------------------------------- residual + LayerNorm
__global__ __launch_bounds__(256) void ln_res(const float* __restrict__ x,
                                              const u16* __restrict__ hb,
                                              float* __restrict__ out,
                                              const float* __restrict__ gamma,
                                              const float* __restrict__ beta)
{
  int mp = blockIdx.x;                 // b*2048 + t
  int b = mp >> 11, t = mp & 2047;
  int xrow = t * 16 + b;
  const fvec4* xr = (const fvec4*)(x + (size_t)xrow * E_DIM);
  const us4* hr = (const us4*)(hb + (size_t)mp * E_DIM);
  fvec4* yr = (fvec4*)(out + (size_t)xrow * E_DIM);
  int tid = threadIdx.x;
  us4 hv = hr[tid];
  fvec4 xv = xr[tid];
  fvec4 s;
  #pragma unroll
  for (int e = 0; e < 4; e++) s[e] = xv[e] + bf2f(hv[e]);
  float sum = s[0] + s[1] + s[2] + s[3];
  float sq  = s[0]*s[0] + s[1]*s[1] + s[2]*s[2] + s[3]*s[3];
  #pragma unroll
  for (int off = 32; off >= 1; off >>= 1) {
    sum += __shfl_xor(sum, off, 64);
    sq  += __shfl_xor(sq, off, 64);
  }
  __shared__ float red[8];
  int lane = tid & 63, wid = tid >> 6;
  if (lane == 0) { red[wid] = sum; red[4 + wid] = sq; }
  __syncthreads();
  sum = red[0] + red[1] + red[2] + red[3];
  sq  = red[4] + red[5] + red[6] + red[7];
  float mean = sum * (1.0f / E_DIM);
  float var  = sq * (1.0f / E_DIM) - mean * mean;
  float rstd = rsqrtf(var + 1e-5f);
  fvec4 g = ((const fvec4*)gamma)[tid];
  fvec4 be = ((const fvec4*)beta)[tid];
  fvec4 o;
  #pragma unroll
  for (int e = 0; e < 4; e++) o[e] = (s[e] - mean) * rstd * g[e] + be[e];
  yr[tid] = o;
}

// ---------------------------------------------------------------- launcher
extern "C" void kernel_launch(void* const* d_in, const int* in_sizes, int n_in,
                              void* d_out, int out_size, void* d_ws, size_t ws_size,
                              hipStream_t stream)
{
  const float* x     = (const float*)d_in[0];
  const float* w1    = (const float*)d_in[1];
  const float* b1    = (const float*)d_in[2];
  const float* ww    = (const float*)d_in[3];
  const float* bw    = (const float*)d_in[4];
  const float* w2    = (const float*)d_in[5];
  const float* b2    = (const float*)d_in[6];
  const float* gamma = (const float*)d_in[7];
  const float* beta  = (const float*)d_in[8];
  float* out = (float*)d_out;

  char* ws = (char*)d_ws;
  u16*   xbt  = (u16*)(ws);                          // 64 MB  xb'[b][t][e]; reused as conv'
  u16*   h1p  = (u16*)(ws + ((size_t)64 << 20));     // 64 MB  h1'[s][t][64]; reused as h2'
  float* wt   = (float*)(ws + ((size_t)128 << 20));  // 64 MB  wt[b][h][t][32] f32
  u16*   w1b  = (u16*)(ws + ((size_t)192 << 20));    // 2 MB
  u16*   w2b  = (u16*)(ws + ((size_t)194 << 20));    // 2 MB
  u16*   wwb  = (u16*)(ws + ((size_t)196 << 20));    // ~1 MB
  u16*   zreg = (u16*)(ws + ((size_t)198 << 20));    // 4 KB zeroed
  u16*   convp = xbt;
  u16*   h2p  = h1p;

  zfill<<<1, 256, 0, stream>>>(zreg);
  cvt_x_tr<<<32768, 256, 0, stream>>>(x, xbt);
  cvt_f32_bf16<<<1024, 256, 0, stream>>>(w1, w1b, (CD * E_DIM) / 4);
  cvt_f32_bf16<<<1024, 256, 0, stream>>>(w2, w2b, (E_DIM * CD) / 4);
  cvt_f32_bf16<<<512,  256, 0, stream>>>(ww, wwb, (NH * KSZ * CD) / 4);

  // h1' = x @ w1^T + b1   (conv-layout bf16)
  gemm256<3, 0, 0><<<512, 512, 0, stream>>>(xbt, w1b, b1, h1p, CD, E_DIM, 0, 4);
  // wt[b][h][t][k] = h1' @ ww^T + bw   (f32, N=496 guarded)
  gemm256<2, 1, 1><<<256, 512, 0, stream>>>(h1p, wwb, bw, wt, NH * KSZ, CD, 0, 2);
  softmax31<<<2048, 256, 0, stream>>>(wt);
  dconv<<<8192, 256, 0, stream>>>(h1p, wt, zreg, convp);
  // h2' = conv' @ w2^T + b2   (bf16, rows m')
  gemm256<1, 0, 1><<<512, 512, 0, stream>>>(convp, w2b, b2, h2p, E_DIM, CD, E_DIM, 4);
  ln_res<<<32768, 256, 0, stream>>>(x, h2p, out, gamma, beta);
}

// Round 8
// 384.120 us; speedup vs baseline: 2.2852x; 1.1041x over previous
//
#include <hip/hip_runtime.h>

#define T_DIM 2048
#define B_DIM 16
#define E_DIM 1024
#define CD    1024
#define NH    16
#define KSZ   31
#define M_DIM 32768
#define SLICE 131072            // 2048*64 elements per (b,h) slice
#define BSTRIDE 2097152         // 2048*1024 = 16*SLICE

typedef unsigned int u32;
typedef unsigned short u16;
typedef __attribute__((ext_vector_type(8))) __bf16 bf16x8;
typedef __attribute__((ext_vector_type(4))) float f32x4;
typedef __attribute__((ext_vector_type(4))) float fvec4;
typedef __attribute__((ext_vector_type(8))) unsigned short us8;
typedef __attribute__((ext_vector_type(4))) unsigned short us4;
typedef __attribute__((ext_vector_type(4))) unsigned int ui4;

__device__ __forceinline__ float bf2f(u16 u) {
  union { float f; u32 i; } c; c.i = ((u32)u) << 16; return c.f;
}
__device__ __forceinline__ u16 f2bf(float f) {
  union { float f; u32 i; } c; c.f = f;
  u32 u = c.i;
  u += 0x7fffu + ((u >> 16) & 1u);   // RNE
  return (u16)(u >> 16);
}

#define GLDS(gp, lp)                                                        \
  __builtin_amdgcn_global_load_lds(                                         \
      (__attribute__((address_space(1))) void*)(gp),                        \
      (__attribute__((address_space(3))) void*)(lp), 16, 0, 0)

// ---------------------------------------------------------------- zero scratch (4 KB)
__global__ __launch_bounds__(256) void zfill(u16* __restrict__ z) {
  ((ui4*)z)[threadIdx.x] = (ui4)(0u);
}

// ---------------------------------------------------------------- cvt f32->bf16 (weights)
__global__ __launch_bounds__(256) void cvt_f32_bf16(const float* __restrict__ src,
                                                    u16* __restrict__ dst, int n4) {
  int i = blockIdx.x * 256 + threadIdx.x;
  int stride = gridDim.x * 256;
  const fvec4* s4 = (const fvec4*)src;
  us4* d4 = (us4*)dst;
  for (; i < n4; i += stride) {
    fvec4 v = s4[i];
    us4 o;
    o[0] = f2bf(v[0]); o[1] = f2bf(v[1]); o[2] = f2bf(v[2]); o[3] = f2bf(v[3]);
    d4[i] = o;
  }
}

// ---------------------------------------------------------------- cvt + row-permute x: [t][b][e] f32 -> [b][t][e] bf16
__global__ __launch_bounds__(256) void cvt_x_tr(const float* __restrict__ x,
                                                u16* __restrict__ xbt) {
  int rr = blockIdx.x;           // t*16+b
  int t = rr >> 4, b = rr & 15;
  const fvec4* src = (const fvec4*)(x + (size_t)rr * E_DIM);
  us4* dst = (us4*)(xbt + ((size_t)b * T_DIM + t) * E_DIM);
  fvec4 v = src[threadIdx.x];
  us4 o;
  o[0] = f2bf(v[0]); o[1] = f2bf(v[1]); o[2] = f2bf(v[2]); o[3] = f2bf(v[3]);
  dst[threadIdx.x] = o;
}

// ---------------------------------------------------------------- 256x256 phased bf16 MFMA GEMM (B^T layout)
// BK=64, 512 threads = 8 waves (2M x 4N), per-wave 128x64 output.
// T1 XCD swizzle + T2 LDS XOR swizzle + T3/T4 counted-vmcnt pipeline + T5 setprio.
// Staging split by consumption order: phase 0 issues {B0..3,A0,A2} of kt+1,
// phase 1 issues {A1,A3}; waits: vmcnt(8) end-phase-1 (curr A1,A3 ready for
// phase 2), vmcnt(2) at boundary (next tile's 6 ready). Never drains to 0.
template<int OUT_MODE, int GUARD_N, int A_CONV>
__global__ __launch_bounds__(512, 2) void gemm256(
    const u16* __restrict__ A, const u16* __restrict__ B,
    const float* __restrict__ bias, void* __restrict__ Cout,
    int N, int K, int ldc, int ntn)
{
  __shared__ u16 sA[2][256 * 64];    // 32 KB per buf
  __shared__ u16 sB[2][256 * 64];    // total 128 KB
  const int tid = threadIdx.x;
  const int lane = tid & 63;
  const int wid = tid >> 6;          // 0..7
  const int wr = wid >> 2;           // M half
  const int wc = wid & 3;            // N quarter

  const int swz = (blockIdx.x & 7) * (gridDim.x >> 3) + (blockIdx.x >> 3);
  const int bm = (swz / ntn) * 256;
  const int bn = (swz % ntn) * 256;

  const int srow = tid >> 3;              // 0..63
  const int scol = (tid & 7) * 8;         // u16 col (16B chunks)
  const int scols = scol ^ ((srow & 7) << 3);   // inverse-swizzled global col

  const u16* gA[4];
  #pragma unroll
  for (int st = 0; st < 4; st++) {
    int rr = bm + st * 64 + srow;
    if (A_CONV)
      gA[st] = A + (size_t)(rr >> 11) * BSTRIDE + (size_t)(rr & 2047) * 64 + scols;
    else
      gA[st] = A + (size_t)rr * K + scols;
  }
  const u16* gB[4];
  #pragma unroll
  for (int st = 0; st < 4; st++) {
    int br = bn + st * 64 + srow;
    if (GUARD_N) br = min(br, N - 1);
    gB[st] = B + (size_t)br * K + scols;
  }
  const int sdst = (tid >> 3) * 64 + scol;   // srow*64 + scol ; add st*4096

  f32x4 acc[8][4];
  #pragma unroll
  for (int i = 0; i < 8; i++)
    #pragma unroll
    for (int j = 0; j < 4; j++) acc[i][j] = (f32x4)(0.0f);

  const int fr = lane & 15;
  const int g8 = (lane >> 4) * 8;          // u16 k-offset within 32-k half
  const int sx = (fr & 7) << 3;            // read-side swizzle (u16)

  const int NT = K >> 6;
  int buf = 0;

  // prologue: stage K-tile 0, full drain (once)
  #pragma unroll
  for (int st = 0; st < 4; st++) GLDS(gB[st], &sB[0][st * 4096 + sdst]);
  GLDS(gA[0], &sA[0][0 * 4096 + sdst]);
  GLDS(gA[2], &sA[0][2 * 4096 + sdst]);
  GLDS(gA[1], &sA[0][1 * 4096 + sdst]);
  GLDS(gA[3], &sA[0][3 * 4096 + sdst]);
  asm volatile("s_waitcnt vmcnt(0)" ::: "memory");
  __builtin_amdgcn_s_barrier();

  for (int kt = 0; kt < NT; kt++) {
    const bool more = (kt + 1 < NT);
    const size_t koA = A_CONV ? (size_t)(kt + 1) * SLICE : (size_t)(kt + 1) * 64;
    const size_t koB = (size_t)(kt + 1) * 64;
    u16* dA = &sA[buf ^ 1][0];
    u16* dB = &sB[buf ^ 1][0];

    // ---------- phase 0: read all B frags + A m0,m1; stage 6 of kt+1; 16 MFMA
    bf16x8 bF[4][2];
    #pragma unroll
    for (int n = 0; n < 4; n++)
      #pragma unroll
      for (int kh = 0; kh < 2; kh++) {
        int row = wc * 64 + n * 16 + fr;
        bF[n][kh] = *(const bf16x8*)&sB[buf][row * 64 + ((kh * 32 + g8) ^ sx)];
      }
    bf16x8 aF[2][2];
    #pragma unroll
    for (int mi = 0; mi < 2; mi++)
      #pragma unroll
      for (int kh = 0; kh < 2; kh++) {
        int row = wr * 128 + mi * 16 + fr;
        aF[mi][kh] = *(const bf16x8*)&sA[buf][row * 64 + ((kh * 32 + g8) ^ sx)];
      }
    if (more) {
      GLDS(gB[0] + koB, dB + 0 * 4096 + sdst);
      GLDS(gB[1] + koB, dB + 1 * 4096 + sdst);
      GLDS(gB[2] + koB, dB + 2 * 4096 + sdst);
      GLDS(gB[3] + koB, dB + 3 * 4096 + sdst);
      GLDS(gA[0] + koA, dA + 0 * 4096 + sdst);
      GLDS(gA[2] + koA, dA + 2 * 4096 + sdst);
    }
    __builtin_amdgcn_s_barrier();
    asm volatile("s_waitcnt lgkmcnt(0)" ::: "memory");
    __builtin_amdgcn_sched_barrier(0);
    __builtin_amdgcn_s_setprio(1);
    #pragma unroll
    for (int mi = 0; mi < 2; mi++)
      #pragma unroll
      for (int n = 0; n < 4; n++)
        #pragma unroll
        for (int kh = 0; kh < 2; kh++)
          acc[mi][n] = __builtin_amdgcn_mfma_f32_16x16x32_bf16(aF[mi][kh], bF[n][kh], acc[mi][n], 0, 0, 0);
    __builtin_amdgcn_s_setprio(0);
    __builtin_amdgcn_sched_barrier(0);
    __builtin_amdgcn_s_barrier();

    // ---------- phases 1..3
    #pragma unroll
    for (int p = 1; p < 4; p++) {
      bf16x8 aG[2][2];
      #pragma unroll
      for (int mi = 0; mi < 2; mi++)
        #pragma unroll
        for (int kh = 0; kh < 2; kh++) {
          int row = wr * 128 + (2 * p + mi) * 16 + fr;
          aG[mi][kh] = *(const bf16x8*)&sA[buf][row * 64 + ((kh * 32 + g8) ^ sx)];
        }
      if (p == 1 && more) {
        GLDS(gA[1] + koA, dA + 1 * 4096 + sdst);
        GLDS(gA[3] + koA, dA + 3 * 4096 + sdst);
      }
      __builtin_amdgcn_s_barrier();
      asm volatile("s_waitcnt lgkmcnt(0)" ::: "memory");
      __builtin_amdgcn_sched_barrier(0);
      __builtin_amdgcn_s_setprio(1);
      #pragma unroll
      for (int mi = 0; mi < 2; mi++)
        #pragma unroll
        for (int n = 0; n < 4; n++)
          #pragma unroll
          for (int kh = 0; kh < 2; kh++)
            acc[2 * p + mi][n] = __builtin_amdgcn_mfma_f32_16x16x32_bf16(aG[mi][kh], bF[n][kh], acc[2 * p + mi][n], 0, 0, 0);
      __builtin_amdgcn_s_setprio(0);
      __builtin_amdgcn_sched_barrier(0);
      if (p == 1) {
        // curr tile's A1,A3 (issued last tile's phase 1) must be done for phase 2
        if (more) { asm volatile("s_waitcnt vmcnt(8)" ::: "memory"); }
        else      { asm volatile("s_waitcnt vmcnt(0)" ::: "memory"); }
      }
      if (p == 3 && more) {
        // next tile's 6 phase-0 loads done; 2 (A1,A3) stay in flight
        asm volatile("s_waitcnt vmcnt(2)" ::: "memory");
      }
      __builtin_amdgcn_s_barrier();
    }
    buf ^= 1;
  }

  const int orow0 = bm + wr * 128 + (lane >> 4) * 4;   // C/D: col=lane&15, row=(lane>>4)*4+q
  const int ocol0 = bn + wc * 64 + fr;
  #pragma unroll
  for (int m = 0; m < 8; m++) {
    #pragma unroll
    for (int n = 0; n < 4; n++) {
      #pragma unroll
      for (int q = 0; q < 4; q++) {
        int row = orow0 + m * 16 + q;
        int col = ocol0 + n * 16;
        if (!GUARD_N || col < N) {
          float v = acc[m][n][q] + bias[col];
          if (OUT_MODE == 1) {
            ((u16*)Cout)[(size_t)row * ldc + col] = f2bf(v);
          } else if (OUT_MODE == 2) {
            int bb = row >> 11, t = row & 2047;
            int hh = col / 31, kk = col - hh * 31;      // compile-time magic div
            ((float*)Cout)[((size_t)((bb * NH + hh) * T_DIM + t)) * 32 + kk] = v;
          } else {                                       // 3: conv layout bf16
            int bb = row >> 11, t = row & 2047;
            ((u16*)Cout)[(size_t)((bb << 4) + (col >> 6)) * SLICE + (size_t)t * 64 + (col & 63)] = f2bf(v);
          }
        }
      }
    }
  }
}

// ---------------------------------------------------------------- dynamic conv + fused softmax
// wt holds LOGITS. Each (b,h,t) w-row is consumed by exactly one block, so
// softmax runs on the staged LDS w-tile (wave 0, one row per thread).
__global__ __launch_bounds__(256) void dconv(const u16* __restrict__ h1,
                                             const float* __restrict__ wt,
                                             const u16* __restrict__ zreg,
                                             u16* __restrict__ outc)
{
  constexpr int TT = 64, HALO = 30, SW = 33;
  int bid = blockIdx.x;
  int tt = bid & 31;            // T/64 = 32
  int s  = bid >> 5;            // b*16+h, 0..255
  int t0 = tt * TT;
  __shared__ u16 hl[96 * 64];   // 12 KB
  __shared__ float wl[TT * SW]; // 8.25 KB
  int tid = threadIdx.x;

  const u16* slice = h1 + (size_t)s * SLICE;
  #pragma unroll
  for (int it = 0; it < 3; it++) {
    int c = it * 256 + tid;
    int row = t0 - HALO + (c >> 3);
    const u16* src = slice + (size_t)row * 64 + (c & 7) * 8;
    if (row < 0) src = zreg + (c & 7) * 8;      // zeroed scratch
    GLDS(src, hl + c * 8);
  }
  const float* wsrc = wt + ((size_t)s * T_DIM + t0) * 32;   // contiguous 8 KB
  #pragma unroll
  for (int it = 0; it < 2; it++) {
    int j = it * 1024 + tid * 4;
    f32x4 v = *(const f32x4*)(wsrc + j);
    int row = j >> 5, col = j & 31;
    *(f32x4*)(&wl[row * SW + col]) = v;
  }
  __syncthreads();

  // fused softmax over the 64 staged rows (wave 0; stride-33 rows -> 2-way banks, free)
  if (tid < TT) {
    float* p = wl + tid * SW;
    float v[KSZ];
    float mx = -1e30f;
    #pragma unroll
    for (int k = 0; k < KSZ; k++) { v[k] = p[k]; mx = fmaxf(mx, v[k]); }
    float sum = 0.f;
    #pragma unroll
    for (int k = 0; k < KSZ; k++) { v[k] = __expf(v[k] - mx); sum += v[k]; }
    float inv = 1.0f / sum;
    #pragma unroll
    for (int k = 0; k < KSZ; k++) p[k] = v[k] * inv;
  }
  __syncthreads();

  int rb = (tid & 7) * 8;           // channel sub-block
  int tl = tid >> 3;                // 0..31

  #pragma unroll
  for (int half = 0; half < 2; half++) {
    const int tb = tl + half * 32;
    const float* wp = wl + tb * SW;
    const u16* hb = hl + tb * 64 + rb;
    float acc[8];
    #pragma unroll
    for (int e = 0; e < 8; e++) acc[e] = 0.f;
    #pragma unroll
    for (int k = 0; k < KSZ; k++) {
      us8 hv = *(const us8*)(hb + k * 64);
      float w = wp[k];
      #pragma unroll
      for (int e = 0; e < 8; e++) acc[e] += w * bf2f(hv[e]);
    }
    us8 o;
    #pragma unroll
    for (int e = 0; e < 8; e++) o[e] = f2bf(acc[e]);
    *(us8*)(outc + (size_t)s * SLICE + (size_t)(t0 + tb) * 64 + rb) = o;
  }
}

// ---------------------------------------------------------------- residual + LayerNorm
__global__ __launch_bounds__(256) void ln_res(const float* __restrict__ x,
                                              const u16* __restrict__ hb,
                                              float* __restrict__ out,
                                              const float* __restrict__ gamma,
                                              const float* __restrict__ beta)
{
  int mp = blockIdx.x;                 // b*2048 + t
  int b = mp >> 11, t = mp & 2047;
  int xrow = t * 16 + b;
  const fvec4* xr = (const fvec4*)(x + (size_t)xrow * E_DIM);
  const us4* hr = (const us4*)(hb + (size_t)mp * E_DIM);
  fvec4* yr = (fvec4*)(out + (size_t)xrow * E_DIM);
  int tid = threadIdx.x;
  us4 hv = hr[tid];
  fvec4 xv = xr[tid];
  fvec4 s;
  #pragma unroll
  for (int e = 0; e < 4; e++) s[e] = xv[e] + bf2f(hv[e]);
  float sum = s[0] + s[1] + s[2] + s[3];
  float sq  = s[0]*s[0] + s[1]*s[1] + s[2]*s[2] + s[3]*s[3];
  #pragma unroll
  for (int off = 32; off >= 1; off >>= 1) {
    sum += __shfl_xor(sum, off, 64);
    sq  += __shfl_xor(sq, off, 64);
  }
  __shared__ float red[8];
  int lane = tid & 63, wid = tid >> 6;
  if (lane == 0) { red[wid] = sum; red[4 + wid] = sq; }
  __syncthreads();
  sum = red[0] + red[1] + red[2] + red[3];
  sq  = red[4] + red[5] + red[6] + red[7];
  float mean = sum * (1.0f / E_DIM);
  float var  = sq * (1.0f / E_DIM) - mean * mean;
  float rstd = rsqrtf(var + 1e-5f);
  fvec4 g = ((const fvec4*)gamma)[tid];
  fvec4 be = ((const fvec4*)beta)[tid];
  fvec4 o;
  #pragma unroll
  for (int e = 0; e < 4; e++) o[e] = (s[e] - mean) * rstd * g[e] + be[e];
  yr[tid] = o;
}

// ---------------------------------------------------------------- launcher
extern "C" void kernel_launch(void* const* d_in, const int* in_sizes, int n_in,
                              void* d_out, int out_size, void* d_ws, size_t ws_size,
                              hipStream_t stream)
{
  const float* x     = (const float*)d_in[0];
  const float* w1    = (const float*)d_in[1];
  const float* b1    = (const float*)d_in[2];
  const float* ww    = (const float*)d_in[3];
  const float* bw    = (const float*)d_in[4];
  const float* w2    = (const float*)d_in[5];
  const float* b2    = (const float*)d_in[6];
  const float* gamma = (const float*)d_in[7];
  const float* beta  = (const float*)d_in[8];
  float* out = (float*)d_out;

  char* ws = (char*)d_ws;
  u16*   xbt  = (u16*)(ws);                          // 64 MB  xb'[b][t][e]; reused as conv'
  u16*   h1p  = (u16*)(ws + ((size_t)64 << 20));     // 64 MB  h1'[s][t][64]; reused as h2'
  float* wt   = (float*)(ws + ((size_t)128 << 20));  // 64 MB  wt[b][h][t][32] f32 logits
  u16*   w1b  = (u16*)(ws + ((size_t)192 << 20));    // 2 MB
  u16*   w2b  = (u16*)(ws + ((size_t)194 << 20));    // 2 MB
  u16*   wwb  = (u16*)(ws + ((size_t)196 << 20));    // ~1 MB
  u16*   zreg = (u16*)(ws + ((size_t)198 << 20));    // 4 KB zeroed
  u16*   convp = xbt;
  u16*   h2p  = h1p;

  zfill<<<1, 256, 0, stream>>>(zreg);
  cvt_x_tr<<<32768, 256, 0, stream>>>(x, xbt);
  cvt_f32_bf16<<<1024, 256, 0, stream>>>(w1, w1b, (CD * E_DIM) / 4);
  cvt_f32_bf16<<<1024, 256, 0, stream>>>(w2, w2b, (E_DIM * CD) / 4);
  cvt_f32_bf16<<<512,  256, 0, stream>>>(ww, wwb, (NH * KSZ * CD) / 4);

  // h1' = x @ w1^T + b1   (conv-layout bf16)
  gemm256<3, 0, 0><<<512, 512, 0, stream>>>(xbt, w1b, b1, h1p, CD, E_DIM, 0, 4);
  // wt[b][h][t][k] = h1' @ ww^T + bw   (f32 logits, N=496 guarded)
  gemm256<2, 1, 1><<<256, 512, 0, stream>>>(h1p, wwb, bw, wt, NH * KSZ, CD, 0, 2);
  dconv<<<8192, 256, 0, stream>>>(h1p, wt, zreg, convp);
  // h2' = conv' @ w2^T + b2   (bf16, rows m')
  gemm256<1, 0, 1><<<512, 512, 0, stream>>>(convp, w2b, b2, h2p, E_DIM, CD, E_DIM, 4);
  ln_res<<<32768, 256, 0, stream>>>(x, h2p, out, gamma, beta);
}

// Round 9
// 373.141 us; speedup vs baseline: 2.3525x; 1.0294x over previous
//
#include <hip/hip_runtime.h>

#define T_DIM 2048
#define B_DIM 16
#define E_DIM 1024
#define CD    1024
#define NH    16
#define KSZ   31
#define M_DIM 32768
#define SLICE 131072            // 2048*64 elements per (b,h) slice
#define BSTRIDE 2097152         // 2048*1024 = 16*SLICE

typedef unsigned int u32;
typedef unsigned short u16;
typedef __attribute__((ext_vector_type(8))) __bf16 bf16x8;
typedef __attribute__((ext_vector_type(4))) float f32x4;
typedef __attribute__((ext_vector_type(4))) float fvec4;
typedef __attribute__((ext_vector_type(8))) unsigned short us8;
typedef __attribute__((ext_vector_type(4))) unsigned short us4;
typedef __attribute__((ext_vector_type(4))) unsigned int ui4;

__device__ __forceinline__ float bf2f(u16 u) {
  union { float f; u32 i; } c; c.i = ((u32)u) << 16; return c.f;
}
__device__ __forceinline__ u16 f2bf(float f) {
  union { float f; u32 i; } c; c.f = f;
  u32 u = c.i;
  u += 0x7fffu + ((u >> 16) & 1u);   // RNE
  return (u16)(u >> 16);
}

#define GLDS(gp, lp)                                                        \
  __builtin_amdgcn_global_load_lds(                                         \
      (__attribute__((address_space(1))) void*)(gp),                        \
      (__attribute__((address_space(3))) void*)(lp), 16, 0, 0)

// ---------------------------------------------------------------- zero scratch (4 KB)
__global__ __launch_bounds__(256) void zfill(u16* __restrict__ z) {
  ((ui4*)z)[threadIdx.x] = (ui4)(0u);
}

// ---------------------------------------------------------------- cvt f32->bf16 (weights)
__global__ __launch_bounds__(256) void cvt_f32_bf16(const float* __restrict__ src,
                                                    u16* __restrict__ dst, int n4) {
  int i = blockIdx.x * 256 + threadIdx.x;
  int stride = gridDim.x * 256;
  const fvec4* s4 = (const fvec4*)src;
  us4* d4 = (us4*)dst;
  for (; i < n4; i += stride) {
    fvec4 v = s4[i];
    us4 o;
    o[0] = f2bf(v[0]); o[1] = f2bf(v[1]); o[2] = f2bf(v[2]); o[3] = f2bf(v[3]);
    d4[i] = o;
  }
}

// ---------------------------------------------------------------- 256x256 phased bf16 MFMA GEMM (B^T layout)
// BK=64, 512 threads = 8 waves (2M x 4N), per-wave 128x64 output.
// T1 XCD swizzle + T2 LDS XOR swizzle + 4-phase schedule + T5 setprio.
// Staging spread evenly: p0:B0B1 p1:B2B3 p2:A0A2 p3:A1A3 (counted waits).
// A_MODE: 1 = conv-layout bf16 via GLDS; 2 = f32 x[t][b][e] reg-staged with
//         inline cvt (loads issued p0/p1, cvt+ds_write p2/p3 — T14 split).
// OUT_MODE: 1 bf16 row-major ldc; 2 wt[b][h][t][32] bf16; 3 conv-layout bf16.
template<int OUT_MODE, int GUARD_N, int A_MODE>
__global__ __launch_bounds__(512, 2) void gemm256(
    const void* __restrict__ Av, const u16* __restrict__ B,
    const float* __restrict__ bias, void* __restrict__ Cout,
    int N, int K, int ldc, int ntn)
{
  __shared__ u16 sA[2][256 * 64];    // 32 KB per buf
  __shared__ u16 sB[2][256 * 64];    // total 128 KB
  const int tid = threadIdx.x;
  const int lane = tid & 63;
  const int wid = tid >> 6;          // 0..7
  const int wr = wid >> 2;           // M half
  const int wc = wid & 3;            // N quarter

  const int swz = (blockIdx.x & 7) * (gridDim.x >> 3) + (blockIdx.x >> 3);
  const int bm = (swz / ntn) * 256;
  const int bn = (swz % ntn) * 256;

  const int srow = tid >> 3;              // 0..63
  const int scol = (tid & 7) * 8;         // u16/f32 col chunk
  const int scols = scol ^ ((srow & 7) << 3);   // pre-swizzled global col (GLDS path)
  const int sdst   = srow * 64 + scol;          // linear LDS dest (GLDS path)
  const int sdst_s = srow * 64 + scols;         // swizzled LDS dest (ds_write path)

  const u16* Ab = (const u16*)Av;
  const float* Af = (const float*)Av;

  const u16* gA[4];
  const float* gX[4];
  #pragma unroll
  for (int st = 0; st < 4; st++) {
    int rr = bm + st * 64 + srow;
    if (A_MODE == 1) {
      gA[st] = Ab + (size_t)(rr >> 11) * BSTRIDE + (size_t)(rr & 2047) * 64 + scols;
      gX[st] = nullptr;
    } else {
      int t = rr & 2047, b = rr >> 11;
      gX[st] = Af + (size_t)(t * 16 + b) * 1024 + scol;   // unswizzled f32 source
      gA[st] = nullptr;
    }
  }
  const u16* gB[4];
  #pragma unroll
  for (int st = 0; st < 4; st++) {
    int br = bn + st * 64 + srow;
    if (GUARD_N) br = min(br, N - 1);
    gB[st] = B + (size_t)br * K + scols;
  }

  f32x4 acc[8][4];
  #pragma unroll
  for (int i = 0; i < 8; i++)
    #pragma unroll
    for (int j = 0; j < 4; j++) acc[i][j] = (f32x4)(0.0f);

  const int fr = lane & 15;
  const int g8 = (lane >> 4) * 8;          // u16 k-offset within 32-k half
  const int sx = (fr & 7) << 3;            // read-side swizzle (u16)

  const int NT = K >> 6;
  int buf = 0;

  // ---------------- prologue: K-tile 0
  #pragma unroll
  for (int st = 0; st < 4; st++) GLDS(gB[st], &sB[0][st * 4096 + sdst]);
  if (A_MODE == 1) {
    #pragma unroll
    for (int st = 0; st < 4; st++) GLDS(gA[st], &sA[0][st * 4096 + sdst]);
    asm volatile("s_waitcnt vmcnt(0)" ::: "memory");
  } else {
    fvec4 q[4][2];
    #pragma unroll
    for (int st = 0; st < 4; st++) {
      q[st][0] = *(const fvec4*)(gX[st]);
      q[st][1] = *(const fvec4*)(gX[st] + 4);
    }
    #pragma unroll
    for (int st = 0; st < 4; st++) {
      us8 o;
      #pragma unroll
      for (int e = 0; e < 4; e++) { o[e] = f2bf(q[st][0][e]); o[e + 4] = f2bf(q[st][1][e]); }
      *(us8*)&sA[0][st * 4096 + sdst_s] = o;
    }
    asm volatile("s_waitcnt vmcnt(0)" ::: "memory");
    asm volatile("s_waitcnt lgkmcnt(0)" ::: "memory");
  }
  __builtin_amdgcn_s_barrier();

  for (int kt = 0; kt < NT; kt++) {
    const bool more = (kt + 1 < NT);
    const size_t koB = (size_t)(kt + 1) * 64;
    const size_t koA = (size_t)(kt + 1) * SLICE;   // conv layout A
    const size_t koX = (size_t)(kt + 1) * 64;      // f32 x
    u16* dA = &sA[buf ^ 1][0];
    u16* dB = &sB[buf ^ 1][0];
    fvec4 xa[4][2];                                // mode-2 in-flight A (statically indexed)

    // ---------- phase 0: all B frags + A m0,m1; stage B0,B1; mode2: load st0,st1
    bf16x8 bF[4][2];
    #pragma unroll
    for (int n = 0; n < 4; n++)
      #pragma unroll
      for (int kh = 0; kh < 2; kh++) {
        int row = wc * 64 + n * 16 + fr;
        bF[n][kh] = *(const bf16x8*)&sB[buf][row * 64 + ((kh * 32 + g8) ^ sx)];
      }
    bf16x8 aF[2][2];
    #pragma unroll
    for (int mi = 0; mi < 2; mi++)
      #pragma unroll
      for (int kh = 0; kh < 2; kh++) {
        int row = wr * 128 + mi * 16 + fr;
        aF[mi][kh] = *(const bf16x8*)&sA[buf][row * 64 + ((kh * 32 + g8) ^ sx)];
      }
    if (more) {
      GLDS(gB[0] + koB, dB + 0 * 4096 + sdst);
      GLDS(gB[1] + koB, dB + 1 * 4096 + sdst);
      if (A_MODE == 2) {
        xa[0][0] = *(const fvec4*)(gX[0] + koX); xa[0][1] = *(const fvec4*)(gX[0] + koX + 4);
        xa[1][0] = *(const fvec4*)(gX[1] + koX); xa[1][1] = *(const fvec4*)(gX[1] + koX + 4);
      }
    }
    __builtin_amdgcn_s_barrier();
    asm volatile("s_waitcnt lgkmcnt(0)" ::: "memory");
    __builtin_amdgcn_sched_barrier(0);
    __builtin_amdgcn_s_setprio(1);
    #pragma unroll
    for (int mi = 0; mi < 2; mi++)
      #pragma unroll
      for (int n = 0; n < 4; n++)
        #pragma unroll
        for (int kh = 0; kh < 2; kh++)
          acc[mi][n] = __builtin_amdgcn_mfma_f32_16x16x32_bf16(aF[mi][kh], bF[n][kh], acc[mi][n], 0, 0, 0);
    __builtin_amdgcn_s_setprio(0);
    __builtin_amdgcn_sched_barrier(0);
    __builtin_amdgcn_s_barrier();

    // ---------- phase 1: A m2,m3; stage B2,B3; mode2: load st2,st3; mode1 wait A1,A3
    {
      bf16x8 aG[2][2];
      #pragma unroll
      for (int mi = 0; mi < 2; mi++)
        #pragma unroll
        for (int kh = 0; kh < 2; kh++) {
          int row = wr * 128 + (2 + mi) * 16 + fr;
          aG[mi][kh] = *(const bf16x8*)&sA[buf][row * 64 + ((kh * 32 + g8) ^ sx)];
        }
      if (more) {
        GLDS(gB[2] + koB, dB + 2 * 4096 + sdst);
        GLDS(gB[3] + koB, dB + 3 * 4096 + sdst);
        if (A_MODE == 2) {
          xa[2][0] = *(const fvec4*)(gX[2] + koX); xa[2][1] = *(const fvec4*)(gX[2] + koX + 4);
          xa[3][0] = *(const fvec4*)(gX[3] + koX); xa[3][1] = *(const fvec4*)(gX[3] + koX + 4);
        }
      }
      __builtin_amdgcn_s_barrier();
      asm volatile("s_waitcnt lgkmcnt(0)" ::: "memory");
      __builtin_amdgcn_sched_barrier(0);
      __builtin_amdgcn_s_setprio(1);
      #pragma unroll
      for (int mi = 0; mi < 2; mi++)
        #pragma unroll
        for (int n = 0; n < 4; n++)
          #pragma unroll
          for (int kh = 0; kh < 2; kh++)
            acc[2 + mi][n] = __builtin_amdgcn_mfma_f32_16x16x32_bf16(aG[mi][kh], bF[n][kh], acc[2 + mi][n], 0, 0, 0);
      __builtin_amdgcn_s_setprio(0);
      __builtin_amdgcn_sched_barrier(0);
      if (A_MODE == 1) {
        if (more) { asm volatile("s_waitcnt vmcnt(4)" ::: "memory"); }
        else      { asm volatile("s_waitcnt vmcnt(0)" ::: "memory"); }
      }
      __builtin_amdgcn_s_barrier();
    }

    // ---------- phase 2: A m4,m5; mode1: stage A0,A2; mode2: cvt+write st0,st1
    {
      bf16x8 aG[2][2];
      #pragma unroll
      for (int mi = 0; mi < 2; mi++)
        #pragma unroll
        for (int kh = 0; kh < 2; kh++) {
          int row = wr * 128 + (4 + mi) * 16 + fr;
          aG[mi][kh] = *(const bf16x8*)&sA[buf][row * 64 + ((kh * 32 + g8) ^ sx)];
        }
      if (more) {
        if (A_MODE == 1) {
          GLDS(gA[0] + koA, dA + 0 * 4096 + sdst);
          GLDS(gA[2] + koA, dA + 2 * 4096 + sdst);
        } else {
          #pragma unroll
          for (int st = 0; st < 2; st++) {
            us8 o;
            #pragma unroll
            for (int e = 0; e < 4; e++) { o[e] = f2bf(xa[st][0][e]); o[e + 4] = f2bf(xa[st][1][e]); }
            *(us8*)(dA + st * 4096 + sdst_s) = o;
          }
        }
      }
      __builtin_amdgcn_s_barrier();
      asm volatile("s_waitcnt lgkmcnt(0)" ::: "memory");
      __builtin_amdgcn_sched_barrier(0);
      __builtin_amdgcn_s_setprio(1);
      #pragma unroll
      for (int mi = 0; mi < 2; mi++)
        #pragma unroll
        for (int n = 0; n < 4; n++)
          #pragma unroll
          for (int kh = 0; kh < 2; kh++)
            acc[4 + mi][n] = __builtin_amdgcn_mfma_f32_16x16x32_bf16(aG[mi][kh], bF[n][kh], acc[4 + mi][n], 0, 0, 0);
      __builtin_amdgcn_s_setprio(0);
      __builtin_amdgcn_sched_barrier(0);
      __builtin_amdgcn_s_barrier();
    }

    // ---------- phase 3: A m6,m7; mode1: stage A1,A3 + vmcnt(2); mode2: write st2,st3 + drain
    {
      bf16x8 aG[2][2];
      #pragma unroll
      for (int mi = 0; mi < 2; mi++)
        #pragma unroll
        for (int kh = 0; kh < 2; kh++) {
          int row = wr * 128 + (6 + mi) * 16 + fr;
          aG[mi][kh] = *(const bf16x8*)&sA[buf][row * 64 + ((kh * 32 + g8) ^ sx)];
        }
      if (more) {
        if (A_MODE == 1) {
          GLDS(gA[1] + koA, dA + 1 * 4096 + sdst);
          GLDS(gA[3] + koA, dA + 3 * 4096 + sdst);
        } else {
          #pragma unroll
          for (int st = 2; st < 4; st++) {
            us8 o;
            #pragma unroll
            for (int e = 0; e < 4; e++) { o[e] = f2bf(xa[st][0][e]); o[e + 4] = f2bf(xa[st][1][e]); }
            *(us8*)(dA + st * 4096 + sdst_s) = o;
          }
        }
      }
      if (A_MODE == 2) {
        if (more) { asm volatile("s_waitcnt vmcnt(0)" ::: "memory"); }   // B GLDS (2-3 phases old)
        asm volatile("s_waitcnt lgkmcnt(0)" ::: "memory");               // writer visibility pre-barrier
      }
      __builtin_amdgcn_s_barrier();
      asm volatile("s_waitcnt lgkmcnt(0)" ::: "memory");
      __builtin_amdgcn_sched_barrier(0);
      __builtin_amdgcn_s_setprio(1);
      #pragma unroll
      for (int mi = 0; mi < 2; mi++)
        #pragma unroll
        for (int n = 0; n < 4; n++)
          #pragma unroll
          for (int kh = 0; kh < 2; kh++)
            acc[6 + mi][n] = __builtin_amdgcn_mfma_f32_16x16x32_bf16(aG[mi][kh], bF[n][kh], acc[6 + mi][n], 0, 0, 0);
      __builtin_amdgcn_s_setprio(0);
      __builtin_amdgcn_sched_barrier(0);
      if (A_MODE == 1 && more) {
        asm volatile("s_waitcnt vmcnt(2)" ::: "memory");   // next tile's B+A0,A2 done; A1,A3 in flight
      }
      __builtin_amdgcn_s_barrier();
    }
    buf ^= 1;
  }

  const int orow0 = bm + wr * 128 + (lane >> 4) * 4;   // C/D: col=lane&15, row=(lane>>4)*4+q
  const int ocol0 = bn + wc * 64 + fr;
  #pragma unroll
  for (int m = 0; m < 8; m++) {
    #pragma unroll
    for (int n = 0; n < 4; n++) {
      #pragma unroll
      for (int q = 0; q < 4; q++) {
        int row = orow0 + m * 16 + q;
        int col = ocol0 + n * 16;
        if (!GUARD_N || col < N) {
          float v = acc[m][n][q] + bias[col];
          if (OUT_MODE == 1) {
            ((u16*)Cout)[(size_t)row * ldc + col] = f2bf(v);
          } else if (OUT_MODE == 2) {               // wt bf16 [b][h][t][32]
            int bb = row >> 11, t = row & 2047;
            int hh = col / 31, kk = col - hh * 31;  // compile-time magic div
            ((u16*)Cout)[((size_t)((bb * NH + hh) * T_DIM + t)) * 32 + kk] = f2bf(v);
          } else {                                  // 3: conv layout bf16
            int bb = row >> 11, t = row & 2047;
            ((u16*)Cout)[(size_t)((bb << 4) + (col >> 6)) * SLICE + (size_t)t * 64 + (col & 63)] = f2bf(v);
          }
        }
      }
    }
  }
}

// ---------------------------------------------------------------- dynamic conv + fused softmax
// wt holds bf16 LOGITS. Each (b,h,t) w-row is consumed by exactly one block:
// stage w-tile to LDS (cvt to f32), softmax in-LDS, then banded aggregation.
__global__ __launch_bounds__(256) void dconv(const u16* __restrict__ h1,
                                             const u16* __restrict__ wt,
                                             const u16* __restrict__ zreg,
                                             u16* __restrict__ outc)
{
  constexpr int TT = 64, HALO = 30, SW = 33;
  int bid = blockIdx.x;
  int tt = bid & 31;            // T/64 = 32
  int s  = bid >> 5;            // b*16+h, 0..255
  int t0 = tt * TT;
  __shared__ u16 hl[96 * 64];   // 12 KB
  __shared__ float wl[TT * SW]; // 8.25 KB
  int tid = threadIdx.x;

  const u16* slice = h1 + (size_t)s * SLICE;
  #pragma unroll
  for (int it = 0; it < 3; it++) {
    int c = it * 256 + tid;
    int row = t0 - HALO + (c >> 3);
    const u16* src = slice + (size_t)row * 64 + (c & 7) * 8;
    if (row < 0) src = zreg + (c & 7) * 8;      // zeroed scratch
    GLDS(src, hl + c * 8);
  }
  {
    const u16* wsrc = wt + ((size_t)s * T_DIM + t0) * 32;   // contiguous 4 KB bf16
    int j = tid * 8;                 // u16 index; 256 threads x 8 = 2048 = 64x32
    us8 v = *(const us8*)(wsrc + j);
    int row = j >> 5, col = j & 31;
    #pragma unroll
    for (int e = 0; e < 8; e++) wl[row * SW + col + e] = bf2f(v[e]);
  }
  __syncthreads();

  // fused softmax over the 64 staged rows (wave 0; stride-33 rows -> 2-way banks, free)
  if (tid < TT) {
    float* p = wl + tid * SW;
    float v[KSZ];
    float mx = -1e30f;
    #pragma unroll
    for (int k = 0; k < KSZ; k++) { v[k] = p[k]; mx = fmaxf(mx, v[k]); }
    float sum = 0.f;
    #pragma unroll
    for (int k = 0; k < KSZ; k++) { v[k] = __expf(v[k] - mx); sum += v[k]; }
    float inv = 1.0f / sum;
    #pragma unroll
    for (int k = 0; k < KSZ; k++) p[k] = v[k] * inv;
  }
  __syncthreads();

  int rb = (tid & 7) * 8;           // channel sub-block
  int tl = tid >> 3;                // 0..31

  #pragma unroll
  for (int half = 0; half < 2; half++) {
    const int tb = tl + half * 32;
    const float* wp = wl + tb * SW;
    const u16* hb = hl + tb * 64 + rb;
    float acc[8];
    #pragma unroll
    for (int e = 0; e < 8; e++) acc[e] = 0.f;
    #pragma unroll
    for (int k = 0; k < KSZ; k++) {
      us8 hv = *(const us8*)(hb + k * 64);
      float w = wp[k];
      #pragma unroll
      for (int e = 0; e < 8; e++) acc[e] += w * bf2f(hv[e]);
    }
    us8 o;
    #pragma unroll
    for (int e = 0; e < 8; e++) o[e] = f2bf(acc[e]);
    // byte offset = half*4096 + tid*16: contiguous 4 KB span per instruction
    *(us8*)(outc + (size_t)s * SLICE + (size_t)(t0 + tb) * 64 + rb) = o;
  }
}

// ---------------------------------------------------------------- residual + LayerNorm
// h2'[m'][e] (m' = b*2048+t, bf16) + x[t*16+b][e] (f32) -> out[t*16+b][e] (f32)
__global__ __launch_bounds__(256) void ln_res(const float* __restrict__ x,
                                              const u16* __restrict__ hb,
                                              float* __restrict__ out,
                                              const float* __restrict__ gamma,
                                              const float* __restrict__ beta)
{
  int mp = blockIdx.x;                 // b*2048 + t
  int b = mp >> 11, t = mp & 2047;
  int xrow = t * 16 + b;
  const fvec4* xr = (const fvec4*)(x + (size_t)xrow * E_DIM);
  const us4* hr = (const us4*)(hb + (size_t)mp * E_DIM);
  fvec4* yr = (fvec4*)(out + (size_t)xrow * E_DIM);
  int tid = threadIdx.x;
  us4 hv = hr[tid];
  fvec4 xv = xr[tid];
  fvec4 s;
  #pragma unroll
  for (int e = 0; e < 4; e++) s[e] = xv[e] + bf2f(hv[e]);
  float sum = s[0] + s[1] + s[2] + s[3];
  float sq  = s[0]*s[0] + s[1]*s[1] + s[2]*s[2] + s[3]*s[3];
  #pragma unroll
  for (int off = 32; off >= 1; off >>= 1) {
    sum += __shfl_xor(sum, off, 64);
    sq  += __shfl_xor(sq, off, 64);
  }
  __shared__ float red[8];
  int lane = tid & 63, wid = tid >> 6;
  if (lane == 0) { red[wid] = sum; red[4 + wid] = sq; }
  __syncthreads();
  sum = red[0] + red[1] + red[2] + red[3];
  sq  = red[4] + red[5] + red[6] + red[7];
  float mean = sum * (1.0f / E_DIM);
  float var  = sq * (1.0f / E_DIM) - mean * mean;
  float rstd = rsqrtf(var + 1e-5f);
  fvec4 g = ((const fvec4*)gamma)[tid];
  fvec4 be = ((const fvec4*)beta)[tid];
  fvec4 o;
  #pragma unroll
  for (int e = 0; e < 4; e++) o[e] = (s[e] - mean) * rstd * g[e] + be[e];
  yr[tid] = o;
}

// ---------------------------------------------------------------- launcher
extern "C" void kernel_launch(void* const* d_in, const int* in_sizes, int n_in,
                              void* d_out, int out_size, void* d_ws, size_t ws_size,
                              hipStream_t stream)
{
  const float* x     = (const float*)d_in[0];
  const float* w1    = (const float*)d_in[1];
  const float* b1    = (const float*)d_in[2];
  const float* ww    = (const float*)d_in[3];
  const float* bw    = (const float*)d_in[4];
  const float* w2    = (const float*)d_in[5];
  const float* b2    = (const float*)d_in[6];
  const float* gamma = (const float*)d_in[7];
  const float* beta  = (const float*)d_in[8];
  float* out = (float*)d_out;

  char* ws = (char*)d_ws;
  u16*   convp = (u16*)(ws);                         // 64 MB  conv' output
  u16*   h1p  = (u16*)(ws + ((size_t)64 << 20));     // 64 MB  h1'[s][t][64]; reused as h2'
  u16*   wt   = (u16*)(ws + ((size_t)128 << 20));    // 32 MB  wt[b][h][t][32] bf16 logits
  u16*   w1b  = (u16*)(ws + ((size_t)192 << 20));    // 2 MB
  u16*   w2b  = (u16*)(ws + ((size_t)194 << 20));    // 2 MB
  u16*   wwb  = (u16*)(ws + ((size_t)196 << 20));    // ~1 MB
  u16*   zreg = (u16*)(ws + ((size_t)198 << 20));    // 4 KB zeroed
  u16*   h2p  = h1p;

  zfill<<<1, 256, 0, stream>>>(zreg);
  cvt_f32_bf16<<<1024, 256, 0, stream>>>(w1, w1b, (CD * E_DIM) / 4);
  cvt_f32_bf16<<<1024, 256, 0, stream>>>(w2, w2b, (E_DIM * CD) / 4);
  cvt_f32_bf16<<<512,  256, 0, stream>>>(ww, wwb, (NH * KSZ * CD) / 4);

  // h1' = x @ w1^T + b1   (A = f32 x reg-staged with inline cvt; conv-layout bf16 out)
  gemm256<3, 0, 2><<<512, 512, 0, stream>>>(x, w1b, b1, h1p, CD, E_DIM, 0, 4);
  // wt[b][h][t][k] = h1' @ ww^T + bw   (bf16 logits, N=496 guarded)
  gemm256<2, 1, 1><<<256, 512, 0, stream>>>(h1p, wwb, bw, wt, NH * KSZ, CD, 0, 2);
  dconv<<<8192, 256, 0, stream>>>(h1p, wt, zreg, convp);
  // h2' = conv' @ w2^T + b2   (bf16, rows m')
  gemm256<1, 0, 1><<<512, 512, 0, stream>>>(convp, w2b, b2, h2p, E_DIM, CD, E_DIM, 4);
  ln_res<<<32768, 256, 0, stream>>>(x, h2p, out, gamma, beta);
}

// Round 10
// 353.864 us; speedup vs baseline: 2.4806x; 1.0545x over previous
//
#include <hip/hip_runtime.h>

#define T_DIM 2048
#define B_DIM 16
#define E_DIM 1024
#define CD    1024
#define NH    16
#define KSZ   31
#define M_DIM 32768
#define SLICE 131072            // 2048*64 elements per (b,h) slice
#define BSTRIDE 2097152         // 2048*1024 = 16*SLICE

typedef unsigned int u32;
typedef unsigned short u16;
typedef __attribute__((ext_vector_type(8))) __bf16 bf16x8;
typedef __attribute__((ext_vector_type(4))) float f32x4;
typedef __attribute__((ext_vector_type(4))) float fvec4;
typedef __attribute__((ext_vector_type(8))) unsigned short us8;
typedef __attribute__((ext_vector_type(4))) unsigned short us4;
typedef __attribute__((ext_vector_type(4))) unsigned int ui4;

__device__ __forceinline__ float bf2f(u16 u) {
  union { float f; u32 i; } c; c.i = ((u32)u) << 16; return c.f;
}
__device__ __forceinline__ u16 f2bf(float f) {
  union { float f; u32 i; } c; c.f = f;
  u32 u = c.i;
  u += 0x7fffu + ((u >> 16) & 1u);   // RNE
  return (u16)(u >> 16);
}

#define GLDS(gp, lp)                                                        \
  __builtin_amdgcn_global_load_lds(                                         \
      (__attribute__((address_space(1))) void*)(gp),                        \
      (__attribute__((address_space(3))) void*)(lp), 16, 0, 0)

// ---------------------------------------------------------------- prep: one launch for all pre-passes
// ranges (fvec4-chunk index): [0,8388608) x cvt+transpose -> xbt[b][t][e] bf16;
// then w1, w2, ww cvt; then 256 ui4 zeroes -> zreg.
__global__ __launch_bounds__(256) void prep(const float* __restrict__ x,
                                            const float* __restrict__ w1,
                                            const float* __restrict__ w2,
                                            const float* __restrict__ ww,
                                            u16* __restrict__ xbt,
                                            u16* __restrict__ w1b,
                                            u16* __restrict__ w2b,
                                            u16* __restrict__ wwb,
                                            u16* __restrict__ zreg)
{
  const int NX = (T_DIM * B_DIM * E_DIM) / 4;          // 8388608
  const int N1 = NX + (CD * E_DIM) / 4;                // +262144
  const int N2 = N1 + (E_DIM * CD) / 4;                // +262144
  const int N3 = N2 + (NH * KSZ * CD) / 4;             // +126976
  int i = blockIdx.x * 256 + threadIdx.x;
  if (i < NX) {
    int rr = i >> 8, c = i & 255;                      // row t*16+b, chunk within row
    int t = rr >> 4, b = rr & 15;
    fvec4 v = ((const fvec4*)x)[i];
    us4 o;
    o[0] = f2bf(v[0]); o[1] = f2bf(v[1]); o[2] = f2bf(v[2]); o[3] = f2bf(v[3]);
    ((us4*)xbt)[(size_t)(b * T_DIM + t) * 256 + c] = o;
  } else if (i < N1) {
    int j = i - NX;
    fvec4 v = ((const fvec4*)w1)[j];
    us4 o;
    o[0] = f2bf(v[0]); o[1] = f2bf(v[1]); o[2] = f2bf(v[2]); o[3] = f2bf(v[3]);
    ((us4*)w1b)[j] = o;
  } else if (i < N2) {
    int j = i - N1;
    fvec4 v = ((const fvec4*)w2)[j];
    us4 o;
    o[0] = f2bf(v[0]); o[1] = f2bf(v[1]); o[2] = f2bf(v[2]); o[3] = f2bf(v[3]);
    ((us4*)w2b)[j] = o;
  } else if (i < N3) {
    int j = i - N2;
    fvec4 v = ((const fvec4*)ww)[j];
    us4 o;
    o[0] = f2bf(v[0]); o[1] = f2bf(v[1]); o[2] = f2bf(v[2]); o[3] = f2bf(v[3]);
    ((us4*)wwb)[j] = o;
  } else {
    ((ui4*)zreg)[i - N3] = (ui4)(0u);
  }
}

// ---------------------------------------------------------------- 256x256 phased bf16 MFMA GEMM (B^T layout)
// BK=64, 512 threads = 8 waves (2M x 4N), per-wave 128x64 output.
// T1 XCD swizzle + T2 LDS XOR swizzle + 4-phase counted-vmcnt + T5 setprio.
// Staging: p0:B0B1 p1:B2B3 p2:A0A2 p3:A1A3; waits vmcnt(4)@p1, vmcnt(2)@p3.
// A_CONV: 0 = row-major stride K; 1 = conv layout A[(b*16+k/64)*SLICE + t*64 + k%64].
// OUT_MODE: 1 bf16 row-major ldc; 2 wt[b][h][t][32] bf16; 3 conv-layout bf16.
template<int OUT_MODE, int GUARD_N, int A_CONV>
__global__ __launch_bounds__(512, 2) void gemm256(
    const u16* __restrict__ A, const u16* __restrict__ B,
    const float* __restrict__ bias, void* __restrict__ Cout,
    int N, int K, int ldc, int ntn)
{
  __shared__ u16 sA[2][256 * 64];    // 32 KB per buf
  __shared__ u16 sB[2][256 * 64];    // total 128 KB
  const int tid = threadIdx.x;
  const int lane = tid & 63;
  const int wid = tid >> 6;          // 0..7
  const int wr = wid >> 2;           // M half
  const int wc = wid & 3;            // N quarter

  const int swz = (blockIdx.x & 7) * (gridDim.x >> 3) + (blockIdx.x >> 3);
  const int bm = (swz / ntn) * 256;
  const int bn = (swz % ntn) * 256;

  const int srow = tid >> 3;              // 0..63
  const int scol = (tid & 7) * 8;         // u16 col (16B chunks)
  const int scols = scol ^ ((srow & 7) << 3);   // pre-swizzled global col
  const int sdst = srow * 64 + scol;            // linear LDS dest; add st*4096

  const u16* gA[4];
  #pragma unroll
  for (int st = 0; st < 4; st++) {
    int rr = bm + st * 64 + srow;
    if (A_CONV)
      gA[st] = A + (size_t)(rr >> 11) * BSTRIDE + (size_t)(rr & 2047) * 64 + scols;
    else
      gA[st] = A + (size_t)rr * K + scols;
  }
  const u16* gB[4];
  #pragma unroll
  for (int st = 0; st < 4; st++) {
    int br = bn + st * 64 + srow;
    if (GUARD_N) br = min(br, N - 1);
    gB[st] = B + (size_t)br * K + scols;
  }

  f32x4 acc[8][4];
  #pragma unroll
  for (int i = 0; i < 8; i++)
    #pragma unroll
    for (int j = 0; j < 4; j++) acc[i][j] = (f32x4)(0.0f);

  const int fr = lane & 15;
  const int g8 = (lane >> 4) * 8;          // u16 k-offset within 32-k half
  const int sx = (fr & 7) << 3;            // read-side swizzle (u16)

  const int NT = K >> 6;
  int buf = 0;

  // prologue: stage K-tile 0, full drain (once)
  #pragma unroll
  for (int st = 0; st < 4; st++) GLDS(gB[st], &sB[0][st * 4096 + sdst]);
  #pragma unroll
  for (int st = 0; st < 4; st++) GLDS(gA[st], &sA[0][st * 4096 + sdst]);
  asm volatile("s_waitcnt vmcnt(0)" ::: "memory");
  __builtin_amdgcn_s_barrier();

  for (int kt = 0; kt < NT; kt++) {
    const bool more = (kt + 1 < NT);
    const size_t koA = A_CONV ? (size_t)(kt + 1) * SLICE : (size_t)(kt + 1) * 64;
    const size_t koB = (size_t)(kt + 1) * 64;
    u16* dA = &sA[buf ^ 1][0];
    u16* dB = &sB[buf ^ 1][0];

    // ---------- phase 0: all B frags + A m0,m1; stage B0,B1
    bf16x8 bF[4][2];
    #pragma unroll
    for (int n = 0; n < 4; n++)
      #pragma unroll
      for (int kh = 0; kh < 2; kh++) {
        int row = wc * 64 + n * 16 + fr;
        bF[n][kh] = *(const bf16x8*)&sB[buf][row * 64 + ((kh * 32 + g8) ^ sx)];
      }
    bf16x8 aF[2][2];
    #pragma unroll
    for (int mi = 0; mi < 2; mi++)
      #pragma unroll
      for (int kh = 0; kh < 2; kh++) {
        int row = wr * 128 + mi * 16 + fr;
        aF[mi][kh] = *(const bf16x8*)&sA[buf][row * 64 + ((kh * 32 + g8) ^ sx)];
      }
    if (more) {
      GLDS(gB[0] + koB, dB + 0 * 4096 + sdst);
      GLDS(gB[1] + koB, dB + 1 * 4096 + sdst);
    }
    __builtin_amdgcn_s_barrier();
    asm volatile("s_waitcnt lgkmcnt(0)" ::: "memory");
    __builtin_amdgcn_sched_barrier(0);
    __builtin_amdgcn_s_setprio(1);
    #pragma unroll
    for (int mi = 0; mi < 2; mi++)
      #pragma unroll
      for (int n = 0; n < 4; n++)
        #pragma unroll
        for (int kh = 0; kh < 2; kh++)
          acc[mi][n] = __builtin_amdgcn_mfma_f32_16x16x32_bf16(aF[mi][kh], bF[n][kh], acc[mi][n], 0, 0, 0);
    __builtin_amdgcn_s_setprio(0);
    __builtin_amdgcn_sched_barrier(0);
    __builtin_amdgcn_s_barrier();

    // ---------- phase 1: A m2,m3; stage B2,B3; wait old A1,A3 done
    {
      bf16x8 aG[2][2];
      #pragma unroll
      for (int mi = 0; mi < 2; mi++)
        #pragma unroll
        for (int kh = 0; kh < 2; kh++) {
          int row = wr * 128 + (2 + mi) * 16 + fr;
          aG[mi][kh] = *(const bf16x8*)&sA[buf][row * 64 + ((kh * 32 + g8) ^ sx)];
        }
      if (more) {
        GLDS(gB[2] + koB, dB + 2 * 4096 + sdst);
        GLDS(gB[3] + koB, dB + 3 * 4096 + sdst);
      }
      __builtin_amdgcn_s_barrier();
      asm volatile("s_waitcnt lgkmcnt(0)" ::: "memory");
      __builtin_amdgcn_sched_barrier(0);
      __builtin_amdgcn_s_setprio(1);
      #pragma unroll
      for (int mi = 0; mi < 2; mi++)
        #pragma unroll
        for (int n = 0; n < 4; n++)
          #pragma unroll
          for (int kh = 0; kh < 2; kh++)
            acc[2 + mi][n] = __builtin_amdgcn_mfma_f32_16x16x32_bf16(aG[mi][kh], bF[n][kh], acc[2 + mi][n], 0, 0, 0);
      __builtin_amdgcn_s_setprio(0);
      __builtin_amdgcn_sched_barrier(0);
      if (more) { asm volatile("s_waitcnt vmcnt(4)" ::: "memory"); }
      else      { asm volatile("s_waitcnt vmcnt(0)" ::: "memory"); }
      __builtin_amdgcn_s_barrier();
    }

    // ---------- phase 2: A m4,m5; stage A0,A2
    {
      bf16x8 aG[2][2];
      #pragma unroll
      for (int mi = 0; mi < 2; mi++)
        #pragma unroll
        for (int kh = 0; kh < 2; kh++) {
          int row = wr * 128 + (4 + mi) * 16 + fr;
          aG[mi][kh] = *(const bf16x8*)&sA[buf][row * 64 + ((kh * 32 + g8) ^ sx)];
        }
      if (more) {
        GLDS(gA[0] + koA, dA + 0 * 4096 + sdst);
        GLDS(gA[2] + koA, dA + 2 * 4096 + sdst);
      }
      __builtin_amdgcn_s_barrier();
      asm volatile("s_waitcnt lgkmcnt(0)" ::: "memory");
      __builtin_amdgcn_sched_barrier(0);
      __builtin_amdgcn_s_setprio(1);
      #pragma unroll
      for (int mi = 0; mi < 2; mi++)
        #pragma unroll
        for (int n = 0; n < 4; n++)
          #pragma unroll
          for (int kh = 0; kh < 2; kh++)
            acc[4 + mi][n] = __builtin_amdgcn_mfma_f32_16x16x32_bf16(aG[mi][kh], bF[n][kh], acc[4 + mi][n], 0, 0, 0);
      __builtin_amdgcn_s_setprio(0);
      __builtin_amdgcn_sched_barrier(0);
      __builtin_amdgcn_s_barrier();
    }

    // ---------- phase 3: A m6,m7; stage A1,A3; boundary vmcnt(2)
    {
      bf16x8 aG[2][2];
      #pragma unroll
      for (int mi = 0; mi < 2; mi++)
        #pragma unroll
        for (int kh = 0; kh < 2; kh++) {
          int row = wr * 128 + (6 + mi) * 16 + fr;
          aG[mi][kh] = *(const bf16x8*)&sA[buf][row * 64 + ((kh * 32 + g8) ^ sx)];
        }
      if (more) {
        GLDS(gA[1] + koA, dA + 1 * 4096 + sdst);
        GLDS(gA[3] + koA, dA + 3 * 4096 + sdst);
      }
      __builtin_amdgcn_s_barrier();
      asm volatile("s_waitcnt lgkmcnt(0)" ::: "memory");
      __builtin_amdgcn_sched_barrier(0);
      __builtin_amdgcn_s_setprio(1);
      #pragma unroll
      for (int mi = 0; mi < 2; mi++)
        #pragma unroll
        for (int n = 0; n < 4; n++)
          #pragma unroll
          for (int kh = 0; kh < 2; kh++)
            acc[6 + mi][n] = __builtin_amdgcn_mfma_f32_16x16x32_bf16(aG[mi][kh], bF[n][kh], acc[6 + mi][n], 0, 0, 0);
      __builtin_amdgcn_s_setprio(0);
      __builtin_amdgcn_sched_barrier(0);
      if (more) {
        asm volatile("s_waitcnt vmcnt(2)" ::: "memory");   // next tile's B+A0,A2 done; A1,A3 in flight
      }
      __builtin_amdgcn_s_barrier();
    }
    buf ^= 1;
  }

  const int orow0 = bm + wr * 128 + (lane >> 4) * 4;   // C/D: col=lane&15, row=(lane>>4)*4+q
  const int ocol0 = bn + wc * 64 + fr;
  #pragma unroll
  for (int m = 0; m < 8; m++) {
    #pragma unroll
    for (int n = 0; n < 4; n++) {
      #pragma unroll
      for (int q = 0; q < 4; q++) {
        int row = orow0 + m * 16 + q;
        int col = ocol0 + n * 16;
        if (!GUARD_N || col < N) {
          float v = acc[m][n][q] + bias[col];
          if (OUT_MODE == 1) {
            ((u16*)Cout)[(size_t)row * ldc + col] = f2bf(v);
          } else if (OUT_MODE == 2) {               // wt bf16 [b][h][t][32]
            int bb = row >> 11, t = row & 2047;
            int hh = col / 31, kk = col - hh * 31;  // compile-time magic div
            ((u16*)Cout)[((size_t)((bb * NH + hh) * T_DIM + t)) * 32 + kk] = f2bf(v);
          } else {                                  // 3: conv layout bf16
            int bb = row >> 11, t = row & 2047;
            ((u16*)Cout)[(size_t)((bb << 4) + (col >> 6)) * SLICE + (size_t)t * 64 + (col & 63)] = f2bf(v);
          }
        }
      }
    }
  }
}

// ---------------------------------------------------------------- dynamic conv + fused softmax
// wt holds bf16 LOGITS. Each (b,h,t) w-row is consumed by exactly one block:
// stage w-tile to LDS (cvt to f32), softmax in-LDS, then banded aggregation.
__global__ __launch_bounds__(256) void dconv(const u16* __restrict__ h1,
                                             const u16* __restrict__ wt,
                                             const u16* __restrict__ zreg,
                                             u16* __restrict__ outc)
{
  constexpr int TT = 64, HALO = 30, SW = 33;
  int bid = blockIdx.x;
  int tt = bid & 31;            // T/64 = 32
  int s  = bid >> 5;            // b*16+h, 0..255
  int t0 = tt * TT;
  __shared__ u16 hl[96 * 64];   // 12 KB
  __shared__ float wl[TT * SW]; // 8.25 KB
  int tid = threadIdx.x;

  const u16* slice = h1 + (size_t)s * SLICE;
  #pragma unroll
  for (int it = 0; it < 3; it++) {
    int c = it * 256 + tid;
    int row = t0 - HALO + (c >> 3);
    const u16* src = slice + (size_t)row * 64 + (c & 7) * 8;
    if (row < 0) src = zreg + (c & 7) * 8;      // zeroed scratch
    GLDS(src, hl + c * 8);
  }
  {
    const u16* wsrc = wt + ((size_t)s * T_DIM + t0) * 32;   // contiguous 4 KB bf16
    int j = tid * 8;                 // u16 index; 256 threads x 8 = 2048 = 64x32
    us8 v = *(const us8*)(wsrc + j);
    int row = j >> 5, col = j & 31;
    #pragma unroll
    for (int e = 0; e < 8; e++) wl[row * SW + col + e] = bf2f(v[e]);
  }
  __syncthreads();

  // fused softmax over the 64 staged rows (wave 0; stride-33 rows -> 2-way banks, free)
  if (tid < TT) {
    float* p = wl + tid * SW;
    float v[KSZ];
    float mx = -1e30f;
    #pragma unroll
    for (int k = 0; k < KSZ; k++) { v[k] = p[k]; mx = fmaxf(mx, v[k]); }
    float sum = 0.f;
    #pragma unroll
    for (int k = 0; k < KSZ; k++) { v[k] = __expf(v[k] - mx); sum += v[k]; }
    float inv = 1.0f / sum;
    #pragma unroll
    for (int k = 0; k < KSZ; k++) p[k] = v[k] * inv;
  }
  __syncthreads();

  int rb = (tid & 7) * 8;           // channel sub-block
  int tl = tid >> 3;                // 0..31

  #pragma unroll
  for (int half = 0; half < 2; half++) {
    const int tb = tl + half * 32;
    const float* wp = wl + tb * SW;
    const u16* hb = hl + tb * 64 + rb;
    float acc[8];
    #pragma unroll
    for (int e = 0; e < 8; e++) acc[e] = 0.f;
    #pragma unroll
    for (int k = 0; k < KSZ; k++) {
      us8 hv = *(const us8*)(hb + k * 64);
      float w = wp[k];
      #pragma unroll
      for (int e = 0; e < 8; e++) acc[e] += w * bf2f(hv[e]);
    }
    us8 o;
    #pragma unroll
    for (int e = 0; e < 8; e++) o[e] = f2bf(acc[e]);
    // byte offset = half*4096 + tid*16: contiguous 4 KB span per instruction
    *(us8*)(outc + (size_t)s * SLICE + (size_t)(t0 + tb) * 64 + rb) = o;
  }
}

// ---------------------------------------------------------------- residual + LayerNorm
// h2'[m'][e] (m' = b*2048+t, bf16) + x[t*16+b][e] (f32) -> out[t*16+b][e] (f32)
__global__ __launch_bounds__(256) void ln_res(const float* __restrict__ x,
                                              const u16* __restrict__ hb,
                                              float* __restrict__ out,
                                              const float* __restrict__ gamma,
                                              const float* __restrict__ beta)
{
  int mp = blockIdx.x;                 // b*2048 + t
  int b = mp >> 11, t = mp & 2047;
  int xrow = t * 16 + b;
  const fvec4* xr = (const fvec4*)(x + (size_t)xrow * E_DIM);
  const us4* hr = (const us4*)(hb + (size_t)mp * E_DIM);
  fvec4* yr = (fvec4*)(out + (size_t)xrow * E_DIM);
  int tid = threadIdx.x;
  us4 hv = hr[tid];
  fvec4 xv = xr[tid];
  fvec4 s;
  #pragma unroll
  for (int e = 0; e < 4; e++) s[e] = xv[e] + bf2f(hv[e]);
  float sum = s[0] + s[1] + s[2] + s[3];
  float sq  = s[0]*s[0] + s[1]*s[1] + s[2]*s[2] + s[3]*s[3];
  #pragma unroll
  for (int off = 32; off >= 1; off >>= 1) {
    sum += __shfl_xor(sum, off, 64);
    sq  += __shfl_xor(sq, off, 64);
  }
  __shared__ float red[8];
  int lane = tid & 63, wid = tid >> 6;
  if (lane == 0) { red[wid] = sum; red[4 + wid] = sq; }
  __syncthreads();
  sum = red[0] + red[1] + red[2] + red[3];
  sq  = red[4] + red[5] + red[6] + red[7];
  float mean = sum * (1.0f / E_DIM);
  float var  = sq * (1.0f / E_DIM) - mean * mean;
  float rstd = rsqrtf(var + 1e-5f);
  fvec4 g = ((const fvec4*)gamma)[tid];
  fvec4 be = ((const fvec4*)beta)[tid];
  fvec4 o;
  #pragma unroll
  for (int e = 0; e < 4; e++) o[e] = (s[e] - mean) * rstd * g[e] + be[e];
  yr[tid] = o;
}

// ---------------------------------------------------------------- launcher
extern "C" void kernel_launch(void* const* d_in, const int* in_sizes, int n_in,
                              void* d_out, int out_size, void* d_ws, size_t ws_size,
                              hipStream_t stream)
{
  const float* x     = (const float*)d_in[0];
  const float* w1    = (const float*)d_in[1];
  const float* b1    = (const float*)d_in[2];
  const float* ww    = (const float*)d_in[3];
  const float* bw    = (const float*)d_in[4];
  const float* w2    = (const float*)d_in[5];
  const float* b2    = (const float*)d_in[6];
  const float* gamma = (const float*)d_in[7];
  const float* beta  = (const float*)d_in[8];
  float* out = (float*)d_out;

  char* ws = (char*)d_ws;
  u16*   xbt  = (u16*)(ws);                          // 64 MB  xb'[b][t][e]; reused as conv'
  u16*   h1p  = (u16*)(ws + ((size_t)64 << 20));     // 64 MB  h1'[s][t][64]; reused as h2'
  u16*   wt   = (u16*)(ws + ((size_t)128 << 20));    // 32 MB  wt[b][h][t][32] bf16 logits
  u16*   w1b  = (u16*)(ws + ((size_t)192 << 20));    // 2 MB
  u16*   w2b  = (u16*)(ws + ((size_t)194 << 20));    // 2 MB
  u16*   wwb  = (u16*)(ws + ((size_t)196 << 20));    // ~1 MB
  u16*   zreg = (u16*)(ws + ((size_t)198 << 20));    // 4 KB zeroed
  u16*   convp = xbt;                                // xbt dead after gemm1
  u16*   h2p  = h1p;                                 // h1p dead after dconv

  // one merged pre-pass: x cvt+transpose, w1/w2/ww cvt, zreg fill
  prep<<<35313, 256, 0, stream>>>(x, w1, w2, ww, xbt, w1b, w2b, wwb, zreg);

  // h1' = x @ w1^T + b1   (conv-layout bf16)
  gemm256<3, 0, 0><<<512, 512, 0, stream>>>(xbt, w1b, b1, h1p, CD, E_DIM, 0, 4);
  // wt[b][h][t][k] = h1' @ ww^T + bw   (bf16 logits, N=496 guarded)
  gemm256<2, 1, 1><<<256, 512, 0, stream>>>(h1p, wwb, bw, wt, NH * KSZ, CD, 0, 2);
  dconv<<<8192, 256, 0, stream>>>(h1p, wt, zreg, convp);
  // h2' = conv' @ w2^T + b2   (bf16, rows m')
  gemm256<1, 0, 1><<<512, 512, 0, stream>>>(convp, w2b, b2, h2p, E_DIM, CD, E_DIM, 4);
  ln_res<<<32768, 256, 0, stream>>>(x, h2p, out, gamma, beta);
}

// Round 11
// 347.717 us; speedup vs baseline: 2.5245x; 1.0177x over previous
//
#include <hip/hip_runtime.h>

#define T_DIM 2048
#define B_DIM 16
#define E_DIM 1024
#define CD    1024
#define NH    16
#define KSZ   31
#define M_DIM 32768
#define SLICE 131072            // 2048*64 elements per (b,h) slice
#define BSTRIDE 2097152         // 2048*1024 = 16*SLICE

typedef unsigned int u32;
typedef unsigned short u16;
typedef __attribute__((ext_vector_type(8))) __bf16 bf16x8;
typedef __attribute__((ext_vector_type(4))) float f32x4;
typedef __attribute__((ext_vector_type(4))) float fvec4;
typedef __attribute__((ext_vector_type(8))) unsigned short us8;
typedef __attribute__((ext_vector_type(4))) unsigned short us4;
typedef __attribute__((ext_vector_type(4))) unsigned int ui4;

__device__ __forceinline__ float bf2f(u16 u) {
  union { float f; u32 i; } c; c.i = ((u32)u) << 16; return c.f;
}
__device__ __forceinline__ u16 f2bf(float f) {
  union { float f; u32 i; } c; c.f = f;
  u32 u = c.i;
  u += 0x7fffu + ((u >> 16) & 1u);   // RNE
  return (u16)(u >> 16);
}

#define GLDS(gp, lp)                                                        \
  __builtin_amdgcn_global_load_lds(                                         \
      (__attribute__((address_space(1))) void*)(gp),                        \
      (__attribute__((address_space(3))) void*)(lp), 16, 0, 0)

// ---------------------------------------------------------------- prep: one launch for all pre-passes
// ranges (fvec4-chunk index): [0,8388608) x cvt+transpose -> xbt[b][t][e] bf16;
// then w1, w2, ww cvt; then 256 ui4 zeroes -> zreg.
__global__ __launch_bounds__(256) void prep(const float* __restrict__ x,
                                            const float* __restrict__ w1,
                                            const float* __restrict__ w2,
                                            const float* __restrict__ ww,
                                            u16* __restrict__ xbt,
                                            u16* __restrict__ w1b,
                                            u16* __restrict__ w2b,
                                            u16* __restrict__ wwb,
                                            u16* __restrict__ zreg)
{
  const int NX = (T_DIM * B_DIM * E_DIM) / 4;          // 8388608
  const int N1 = NX + (CD * E_DIM) / 4;                // +262144
  const int N2 = N1 + (E_DIM * CD) / 4;                // +262144
  const int N3 = N2 + (NH * KSZ * CD) / 4;             // +126976
  int i = blockIdx.x * 256 + threadIdx.x;
  if (i < NX) {
    int rr = i >> 8, c = i & 255;                      // row t*16+b, chunk within row
    int t = rr >> 4, b = rr & 15;
    fvec4 v = ((const fvec4*)x)[i];
    us4 o;
    o[0] = f2bf(v[0]); o[1] = f2bf(v[1]); o[2] = f2bf(v[2]); o[3] = f2bf(v[3]);
    ((us4*)xbt)[(size_t)(b * T_DIM + t) * 256 + c] = o;
  } else if (i < N1) {
    int j = i - NX;
    fvec4 v = ((const fvec4*)w1)[j];
    us4 o;
    o[0] = f2bf(v[0]); o[1] = f2bf(v[1]); o[2] = f2bf(v[2]); o[3] = f2bf(v[3]);
    ((us4*)w1b)[j] = o;
  } else if (i < N2) {
    int j = i - N1;
    fvec4 v = ((const fvec4*)w2)[j];
    us4 o;
    o[0] = f2bf(v[0]); o[1] = f2bf(v[1]); o[2] = f2bf(v[2]); o[3] = f2bf(v[3]);
    ((us4*)w2b)[j] = o;
  } else if (i < N3) {
    int j = i - N2;
    fvec4 v = ((const fvec4*)ww)[j];
    us4 o;
    o[0] = f2bf(v[0]); o[1] = f2bf(v[1]); o[2] = f2bf(v[2]); o[3] = f2bf(v[3]);
    ((us4*)wwb)[j] = o;
  } else {
    ((ui4*)zreg)[i - N3] = (ui4)(0u);
  }
}

// ---------------------------------------------------------------- 256x256 phased bf16 MFMA GEMM (B^T layout)
// BK=64, 512 threads = 8 waves (2M x 4N), per-wave 128x64 output.
// T1 XCD swizzle + T2 LDS XOR swizzle + 4-phase counted-vmcnt + T5 setprio.
// Staging: p0:B0B1 p1:B2B3 p2:A0A2 p3:A1A3; waits vmcnt(4)@p1, vmcnt(2)@p3.
// A_CONV: 0 = row-major stride K; 1 = conv layout A[(b*16+k/64)*SLICE + t*64 + k%64].
// OUT_MODE: 1 bf16 row-major ldc; 2 wt[b][h][t][32] bf16; 3 conv-layout bf16.
template<int OUT_MODE, int GUARD_N, int A_CONV>
__global__ __launch_bounds__(512, 2) void gemm256(
    const u16* __restrict__ A, const u16* __restrict__ B,
    const float* __restrict__ bias, void* __restrict__ Cout,
    int N, int K, int ldc, int ntn)
{
  __shared__ u16 sA[2][256 * 64];    // 32 KB per buf
  __shared__ u16 sB[2][256 * 64];    // total 128 KB
  const int tid = threadIdx.x;
  const int lane = tid & 63;
  const int wid = tid >> 6;          // 0..7
  const int wr = wid >> 2;           // M half
  const int wc = wid & 3;            // N quarter

  const int swz = (blockIdx.x & 7) * (gridDim.x >> 3) + (blockIdx.x >> 3);
  const int bm = (swz / ntn) * 256;
  const int bn = (swz % ntn) * 256;

  const int srow = tid >> 3;              // 0..63
  const int scol = (tid & 7) * 8;         // u16 col (16B chunks)
  const int scols = scol ^ ((srow & 7) << 3);   // pre-swizzled global col
  const int sdst = srow * 64 + scol;            // linear LDS dest; add st*4096

  const u16* gA[4];
  #pragma unroll
  for (int st = 0; st < 4; st++) {
    int rr = bm + st * 64 + srow;
    if (A_CONV)
      gA[st] = A + (size_t)(rr >> 11) * BSTRIDE + (size_t)(rr & 2047) * 64 + scols;
    else
      gA[st] = A + (size_t)rr * K + scols;
  }
  const u16* gB[4];
  #pragma unroll
  for (int st = 0; st < 4; st++) {
    int br = bn + st * 64 + srow;
    if (GUARD_N) br = min(br, N - 1);
    gB[st] = B + (size_t)br * K + scols;
  }

  f32x4 acc[8][4];
  #pragma unroll
  for (int i = 0; i < 8; i++)
    #pragma unroll
    for (int j = 0; j < 4; j++) acc[i][j] = (f32x4)(0.0f);

  const int fr = lane & 15;
  const int g8 = (lane >> 4) * 8;          // u16 k-offset within 32-k half
  const int sx = (fr & 7) << 3;            // read-side swizzle (u16)

  const int NT = K >> 6;
  int buf = 0;

  // prologue: stage K-tile 0, full drain (once)
  #pragma unroll
  for (int st = 0; st < 4; st++) GLDS(gB[st], &sB[0][st * 4096 + sdst]);
  #pragma unroll
  for (int st = 0; st < 4; st++) GLDS(gA[st], &sA[0][st * 4096 + sdst]);
  asm volatile("s_waitcnt vmcnt(0)" ::: "memory");
  __builtin_amdgcn_s_barrier();

  for (int kt = 0; kt < NT; kt++) {
    const bool more = (kt + 1 < NT);
    const size_t koA = A_CONV ? (size_t)(kt + 1) * SLICE : (size_t)(kt + 1) * 64;
    const size_t koB = (size_t)(kt + 1) * 64;
    u16* dA = &sA[buf ^ 1][0];
    u16* dB = &sB[buf ^ 1][0];

    // ---------- phase 0: all B frags + A m0,m1; stage B0,B1
    bf16x8 bF[4][2];
    #pragma unroll
    for (int n = 0; n < 4; n++)
      #pragma unroll
      for (int kh = 0; kh < 2; kh++) {
        int row = wc * 64 + n * 16 + fr;
        bF[n][kh] = *(const bf16x8*)&sB[buf][row * 64 + ((kh * 32 + g8) ^ sx)];
      }
    bf16x8 aF[2][2];
    #pragma unroll
    for (int mi = 0; mi < 2; mi++)
      #pragma unroll
      for (int kh = 0; kh < 2; kh++) {
        int row = wr * 128 + mi * 16 + fr;
        aF[mi][kh] = *(const bf16x8*)&sA[buf][row * 64 + ((kh * 32 + g8) ^ sx)];
      }
    if (more) {
      GLDS(gB[0] + koB, dB + 0 * 4096 + sdst);
      GLDS(gB[1] + koB, dB + 1 * 4096 + sdst);
    }
    __builtin_amdgcn_s_barrier();
    asm volatile("s_waitcnt lgkmcnt(0)" ::: "memory");
    __builtin_amdgcn_sched_barrier(0);
    __builtin_amdgcn_s_setprio(1);
    #pragma unroll
    for (int mi = 0; mi < 2; mi++)
      #pragma unroll
      for (int n = 0; n < 4; n++)
        #pragma unroll
        for (int kh = 0; kh < 2; kh++)
          acc[mi][n] = __builtin_amdgcn_mfma_f32_16x16x32_bf16(aF[mi][kh], bF[n][kh], acc[mi][n], 0, 0, 0);
    __builtin_amdgcn_s_setprio(0);
    __builtin_amdgcn_sched_barrier(0);
    __builtin_amdgcn_s_barrier();

    // ---------- phase 1: A m2,m3; stage B2,B3; wait old A1,A3 done
    {
      bf16x8 aG[2][2];
      #pragma unroll
      for (int mi = 0; mi < 2; mi++)
        #pragma unroll
        for (int kh = 0; kh < 2; kh++) {
          int row = wr * 128 + (2 + mi) * 16 + fr;
          aG[mi][kh] = *(const bf16x8*)&sA[buf][row * 64 + ((kh * 32 + g8) ^ sx)];
        }
      if (more) {
        GLDS(gB[2] + koB, dB + 2 * 4096 + sdst);
        GLDS(gB[3] + koB, dB + 3 * 4096 + sdst);
      }
      __builtin_amdgcn_s_barrier();
      asm volatile("s_waitcnt lgkmcnt(0)" ::: "memory");
      __builtin_amdgcn_sched_barrier(0);
      __builtin_amdgcn_s_setprio(1);
      #pragma unroll
      for (int mi = 0; mi < 2; mi++)
        #pragma unroll
        for (int n = 0; n < 4; n++)
          #pragma unroll
          for (int kh = 0; kh < 2; kh++)
            acc[2 + mi][n] = __builtin_amdgcn_mfma_f32_16x16x32_bf16(aG[mi][kh], bF[n][kh], acc[2 + mi][n], 0, 0, 0);
      __builtin_amdgcn_s_setprio(0);
      __builtin_amdgcn_sched_barrier(0);
      if (more) { asm volatile("s_waitcnt vmcnt(4)" ::: "memory"); }
      else      { asm volatile("s_waitcnt vmcnt(0)" ::: "memory"); }
      __builtin_amdgcn_s_barrier();
    }

    // ---------- phase 2: A m4,m5; stage A0,A2
    {
      bf16x8 aG[2][2];
      #pragma unroll
      for (int mi = 0; mi < 2; mi++)
        #pragma unroll
        for (int kh = 0; kh < 2; kh++) {
          int row = wr * 128 + (4 + mi) * 16 + fr;
          aG[mi][kh] = *(const bf16x8*)&sA[buf][row * 64 + ((kh * 32 + g8) ^ sx)];
        }
      if (more) {
        GLDS(gA[0] + koA, dA + 0 * 4096 + sdst);
        GLDS(gA[2] + koA, dA + 2 * 4096 + sdst);
      }
      __builtin_amdgcn_s_barrier();
      asm volatile("s_waitcnt lgkmcnt(0)" ::: "memory");
      __builtin_amdgcn_sched_barrier(0);
      __builtin_amdgcn_s_setprio(1);
      #pragma unroll
      for (int mi = 0; mi < 2; mi++)
        #pragma unroll
        for (int n = 0; n < 4; n++)
          #pragma unroll
          for (int kh = 0; kh < 2; kh++)
            acc[4 + mi][n] = __builtin_amdgcn_mfma_f32_16x16x32_bf16(aG[mi][kh], bF[n][kh], acc[4 + mi][n], 0, 0, 0);
      __builtin_amdgcn_s_setprio(0);
      __builtin_amdgcn_sched_barrier(0);
      __builtin_amdgcn_s_barrier();
    }

    // ---------- phase 3: A m6,m7; stage A1,A3; boundary vmcnt(2)
    {
      bf16x8 aG[2][2];
      #pragma unroll
      for (int mi = 0; mi < 2; mi++)
        #pragma unroll
        for (int kh = 0; kh < 2; kh++) {
          int row = wr * 128 + (6 + mi) * 16 + fr;
          aG[mi][kh] = *(const bf16x8*)&sA[buf][row * 64 + ((kh * 32 + g8) ^ sx)];
        }
      if (more) {
        GLDS(gA[1] + koA, dA + 1 * 4096 + sdst);
        GLDS(gA[3] + koA, dA + 3 * 4096 + sdst);
      }
      __builtin_amdgcn_s_barrier();
      asm volatile("s_waitcnt lgkmcnt(0)" ::: "memory");
      __builtin_amdgcn_sched_barrier(0);
      __builtin_amdgcn_s_setprio(1);
      #pragma unroll
      for (int mi = 0; mi < 2; mi++)
        #pragma unroll
        for (int n = 0; n < 4; n++)
          #pragma unroll
          for (int kh = 0; kh < 2; kh++)
            acc[6 + mi][n] = __builtin_amdgcn_mfma_f32_16x16x32_bf16(aG[mi][kh], bF[n][kh], acc[6 + mi][n], 0, 0, 0);
      __builtin_amdgcn_s_setprio(0);
      __builtin_amdgcn_sched_barrier(0);
      if (more) {
        asm volatile("s_waitcnt vmcnt(2)" ::: "memory");   // next tile's B+A0,A2 done; A1,A3 in flight
      }
      __builtin_amdgcn_s_barrier();
    }
    buf ^= 1;
  }

  const int orow0 = bm + wr * 128 + (lane >> 4) * 4;   // C/D: col=lane&15, row=(lane>>4)*4+q
  const int ocol0 = bn + wc * 64 + fr;
  #pragma unroll
  for (int m = 0; m < 8; m++) {
    #pragma unroll
    for (int n = 0; n < 4; n++) {
      #pragma unroll
      for (int q = 0; q < 4; q++) {
        int row = orow0 + m * 16 + q;
        int col = ocol0 + n * 16;
        if (!GUARD_N || col < N) {
          float v = acc[m][n][q] + bias[col];
          if (OUT_MODE == 1) {
            ((u16*)Cout)[(size_t)row * ldc + col] = f2bf(v);
          } else if (OUT_MODE == 2) {               // wt bf16 [b][h][t][32]
            int bb = row >> 11, t = row & 2047;
            int hh = col / 31, kk = col - hh * 31;  // compile-time magic div
            ((u16*)Cout)[((size_t)((bb * NH + hh) * T_DIM + t)) * 32 + kk] = f2bf(v);
          } else {                                  // 3: conv layout bf16
            int bb = row >> 11, t = row & 2047;
            ((u16*)Cout)[(size_t)((bb << 4) + (col >> 6)) * SLICE + (size_t)t * 64 + (col & 63)] = f2bf(v);
          }
        }
      }
    }
  }
}

// ---------------------------------------------------------------- dynamic conv + fused softmax (TT=128)
// wt holds bf16 LOGITS. Each (b,h,t) w-row is consumed by exactly one block:
// stage w-tile to LDS (cvt to f32), softmax in-LDS, then banded aggregation.
__global__ __launch_bounds__(256) void dconv(const u16* __restrict__ h1,
                                             const u16* __restrict__ wt,
                                             const u16* __restrict__ zreg,
                                             u16* __restrict__ outc)
{
  constexpr int TT = 128, HALO = 30, SW = 33;
  int bid = blockIdx.x;
  int tt = bid & 15;            // T/128 = 16
  int b  = (bid >> 4) & 15;
  int h  = bid >> 8;            // 0..15
  int s  = b * 16 + h;
  int t0 = tt * TT;
  __shared__ u16 hl[(TT + HALO) * 64];   // 158 x 128B = 19.75 KB
  __shared__ float wl[TT * SW];          // 16.5 KB
  int tid = threadIdx.x;

  const u16* slice = h1 + (size_t)s * SLICE;
  #pragma unroll
  for (int it = 0; it < 5; it++) {
    int c = it * 256 + tid;
    if (c < (TT + HALO) * 8) {
      int row = t0 - HALO + (c >> 3);
      const u16* src = slice + (size_t)row * 64 + (c & 7) * 8;
      if (row < 0) src = zreg + (c & 7) * 8;      // zeroed scratch
      GLDS(src, hl + c * 8);
    }
  }
  {
    const u16* wsrc = wt + ((size_t)s * T_DIM + t0) * 32;   // contiguous 8 KB bf16
    #pragma unroll
    for (int it = 0; it < 2; it++) {
      int j = (it * 256 + tid) * 8;    // u16 index; 512 chunks = 128x32
      us8 v = *(const us8*)(wsrc + j);
      int row = j >> 5, col = j & 31;
      #pragma unroll
      for (int e = 0; e < 8; e++) wl[row * SW + col + e] = bf2f(v[e]);
    }
  }
  __syncthreads();

  // fused softmax over the 128 staged rows (2 waves; stride-33 rows -> 2-way banks, free)
  if (tid < TT) {
    float* p = wl + tid * SW;
    float v[KSZ];
    float mx = -1e30f;
    #pragma unroll
    for (int k = 0; k < KSZ; k++) { v[k] = p[k]; mx = fmaxf(mx, v[k]); }
    float sum = 0.f;
    #pragma unroll
    for (int k = 0; k < KSZ; k++) { v[k] = __expf(v[k] - mx); sum += v[k]; }
    float inv = 1.0f / sum;
    #pragma unroll
    for (int k = 0; k < KSZ; k++) p[k] = v[k] * inv;
  }
  __syncthreads();

  int rb = (tid & 7) * 8;           // channel sub-block
  int tl = tid >> 3;                // 0..31

  #pragma unroll
  for (int half = 0; half < 4; half++) {
    const int tb = tl + half * 32;
    const float* wp = wl + tb * SW;
    const u16* hb = hl + tb * 64 + rb;
    float acc[8];
    #pragma unroll
    for (int e = 0; e < 8; e++) acc[e] = 0.f;
    #pragma unroll
    for (int k = 0; k < KSZ; k++) {
      us8 hv = *(const us8*)(hb + k * 64);
      float w = wp[k];
      #pragma unroll
      for (int e = 0; e < 8; e++) acc[e] += w * bf2f(hv[e]);
    }
    us8 o;
    #pragma unroll
    for (int e = 0; e < 8; e++) o[e] = f2bf(acc[e]);
    // byte offset = half*4096 + tid*16: contiguous 4 KB span per instruction
    *(us8*)(outc + (size_t)s * SLICE + (size_t)(t0 + tb) * 64 + rb) = o;
  }
}

// ---------------------------------------------------------------- residual + LayerNorm (bf16 x + bf16 h)
// h2'[m'][e] + xbt[m'][e] (both bf16, m' = b*2048+t) -> out[t*16+b][e] (f32)
__global__ __launch_bounds__(256) void ln_res(const u16* __restrict__ xb,
                                              const u16* __restrict__ hb,
                                              float* __restrict__ out,
                                              const float* __restrict__ gamma,
                                              const float* __restrict__ beta)
{
  int mp = blockIdx.x;                 // b*2048 + t
  int b = mp >> 11, t = mp & 2047;
  int xrow = t * 16 + b;
  const us4* xr = (const us4*)(xb + (size_t)mp * E_DIM);
  const us4* hr = (const us4*)(hb + (size_t)mp * E_DIM);
  fvec4* yr = (fvec4*)(out + (size_t)xrow * E_DIM);
  int tid = threadIdx.x;
  us4 hv = hr[tid];
  us4 xv = xr[tid];
  fvec4 s;
  #pragma unroll
  for (int e = 0; e < 4; e++) s[e] = bf2f(xv[e]) + bf2f(hv[e]);
  float sum = s[0] + s[1] + s[2] + s[3];
  float sq  = s[0]*s[0] + s[1]*s[1] + s[2]*s[2] + s[3]*s[3];
  #pragma unroll
  for (int off = 32; off >= 1; off >>= 1) {
    sum += __shfl_xor(sum, off, 64);
    sq  += __shfl_xor(sq, off, 64);
  }
  __shared__ float red[8];
  int lane = tid & 63, wid = tid >> 6;
  if (lane == 0) { red[wid] = sum; red[4 + wid] = sq; }
  __syncthreads();
  sum = red[0] + red[1] + red[2] + red[3];
  sq  = red[4] + red[5] + red[6] + red[7];
  float mean = sum * (1.0f / E_DIM);
  float var  = sq * (1.0f / E_DIM) - mean * mean;
  float rstd = rsqrtf(var + 1e-5f);
  fvec4 g = ((const fvec4*)gamma)[tid];
  fvec4 be = ((const fvec4*)beta)[tid];
  fvec4 o;
  #pragma unroll
  for (int e = 0; e < 4; e++) o[e] = (s[e] - mean) * rstd * g[e] + be[e];
  yr[tid] = o;
}

// ---------------------------------------------------------------- launcher
extern "C" void kernel_launch(void* const* d_in, const int* in_sizes, int n_in,
                              void* d_out, int out_size, void* d_ws, size_t ws_size,
                              hipStream_t stream)
{
  const float* x     = (const float*)d_in[0];
  const float* w1    = (const float*)d_in[1];
  const float* b1    = (const float*)d_in[2];
  const float* ww    = (const float*)d_in[3];
  const float* bw    = (const float*)d_in[4];
  const float* w2    = (const float*)d_in[5];
  const float* b2    = (const float*)d_in[6];
  const float* gamma = (const float*)d_in[7];
  const float* beta  = (const float*)d_in[8];
  float* out = (float*)d_out;

  char* ws = (char*)d_ws;
  u16*   xbt  = (u16*)(ws);                          // 64 MB  xb'[b][t][e] (kept for ln_res)
  u16*   h1p  = (u16*)(ws + ((size_t)64 << 20));     // 64 MB  h1'[s][t][64]; reused as h2'
  u16*   wt   = (u16*)(ws + ((size_t)128 << 20));    // 32 MB  wt[b][h][t][32] bf16 logits
  u16*   convp = (u16*)(ws + ((size_t)160 << 20));   // 64 MB  conv'
  u16*   w1b  = (u16*)(ws + ((size_t)224 << 20));    // 2 MB
  u16*   w2b  = (u16*)(ws + ((size_t)226 << 20));    // 2 MB
  u16*   wwb  = (u16*)(ws + ((size_t)228 << 20));    // ~1 MB
  u16*   zreg = (u16*)(ws + ((size_t)230 << 20));    // 4 KB zeroed
  u16*   h2p  = h1p;                                 // h1p dead after dconv

  // one merged pre-pass: x cvt+transpose, w1/w2/ww cvt, zreg fill
  prep<<<35313, 256, 0, stream>>>(x, w1, w2, ww, xbt, w1b, w2b, wwb, zreg);

  // h1' = x @ w1^T + b1   (conv-layout bf16)
  gemm256<3, 0, 0><<<512, 512, 0, stream>>>(xbt, w1b, b1, h1p, CD, E_DIM, 0, 4);
  // wt[b][h][t][k] = h1' @ ww^T + bw   (bf16 logits, N=496 guarded)
  gemm256<2, 1, 1><<<256, 512, 0, stream>>>(h1p, wwb, bw, wt, NH * KSZ, CD, 0, 2);
  dconv<<<4096, 256, 0, stream>>>(h1p, wt, zreg, convp);
  // h2' = conv' @ w2^T + b2   (bf16, rows m')
  gemm256<1, 0, 1><<<512, 512, 0, stream>>>(convp, w2b, b2, h2p, E_DIM, CD, E_DIM, 4);
  ln_res<<<32768, 256, 0, stream>>>(xbt, h2p, out, gamma, beta);
}